// Round 1
// baseline (999.849 us; speedup 1.0000x reference)
//
#include <hip/hip_runtime.h>
#include <hip/hip_bf16.h>

// Problem: B=4, N=4096, D_MODEL=1024, H=16, DEPTH=64 (linear attention + LN)
// Pipeline: wtrans -> gemm(QKV, elu+1 on Q/K) -> qsum -> ktq -> stagec -> gemm(Wo) -> LN

typedef __attribute__((ext_vector_type(8))) short short8;
typedef __attribute__((ext_vector_type(4))) float floatx4;
typedef __attribute__((ext_vector_type(4))) unsigned short ushortx4;

#define DEVINL __device__ __forceinline__

DEVINL unsigned short f2bf(float f) {
  unsigned int u = __builtin_bit_cast(unsigned int, f);
  u += 0x7fffu + ((u >> 16) & 1u);            // RNE
  return (unsigned short)(u >> 16);
}
DEVINL float bf2f(unsigned short h) {
  unsigned int u = ((unsigned int)h) << 16;
  return __builtin_bit_cast(float, u);
}
// async global->LDS, 16B per lane; LDS dest = wave-uniform base + lane*16
DEVINL void g2l16(const void* g, void* l) {
  __builtin_amdgcn_global_load_lds((const __attribute__((address_space(1))) void*)g,
                                   (__attribute__((address_space(3))) void*)l, 16, 0, 0);
}

// ---------------- weight transpose + fp32->bf16 ----------------
struct W4 { const float* w[4]; };

__global__ __launch_bounds__(256) void wtrans_kernel(W4 wp, unsigned short* wt) {
  const int z = blockIdx.z;
  const float* W = wp.w[z];
  unsigned short* WT = wt + (size_t)z * 1024 * 1024;
  __shared__ float tile[32][33];
  const int bx = blockIdx.x, by = blockIdx.y;
  const int t = threadIdx.x, r = t >> 5, c = t & 31;
#pragma unroll
  for (int p = 0; p < 4; ++p)
    tile[p * 8 + r][c] = W[(size_t)(by * 32 + p * 8 + r) * 1024 + bx * 32 + c];
  __syncthreads();
#pragma unroll
  for (int p = 0; p < 4; ++p)
    WT[(size_t)(bx * 32 + p * 8 + r) * 1024 + by * 32 + c] = f2bf(tile[c][p * 8 + r]);
}

// ---------------- main GEMM: C[M,N] = A[M,K] * BT[N,K]^T + bias (opt elu+1) ----------------
struct GArgs {
  const void* A[3];
  const unsigned short* BT[3];
  const float* bias[3];
  unsigned short* C[3];
  int act[3];
};

template <bool AF32>
__global__ __launch_bounds__(256) void gemm_bt_kernel(GArgs g, int M, int N, int K) {
  const int z = blockIdx.z;
  const unsigned short* BT = g.BT[z];
  const float* bias = g.bias[z];
  unsigned short* C = g.C[z];
  const int act = g.act[z];

  const int n0 = blockIdx.x * 128;
  const int m0 = blockIdx.y * 128;
  __shared__ unsigned short lA[128 * 32];
  __shared__ unsigned short lB[128 * 32];
  const int t = threadIdx.x, lane = t & 63, wave = t >> 6;
  const int wm = wave >> 1, wn = wave & 1;

  floatx4 acc[4][4] = {};

  const int srow = lane >> 2;        // row-in-chunk for g2l staging
  const int scol = (lane & 3) * 8;   // elem col

  for (int k0 = 0; k0 < K; k0 += 32) {
    __syncthreads();
    // stage B tile (bf16) via global_load_lds: 8 chunks of 16 rows, 2 per wave
#pragma unroll
    for (int i = 0; i < 2; ++i) {
      const int c = wave * 2 + i;
      const unsigned short* gp = BT + (size_t)(n0 + c * 16 + srow) * K + (k0 + scol);
      g2l16(gp, (void*)&lB[c * 512]);
    }
    if constexpr (AF32) {
      // A is fp32 in global: load float4, convert, ds_write bf16x4
      const float* Af = (const float*)g.A[z];
#pragma unroll
      for (int i = 0; i < 4; ++i) {
        const int e = i * 1024 + t * 4;
        const int row = e >> 5, col = e & 31;
        const float4 v = *(const float4*)(Af + (size_t)(m0 + row) * K + (k0 + col));
        ushortx4 hv;
        hv.x = f2bf(v.x); hv.y = f2bf(v.y); hv.z = f2bf(v.z); hv.w = f2bf(v.w);
        *(ushortx4*)&lA[row * 32 + col] = hv;
      }
    } else {
      const unsigned short* Ab = (const unsigned short*)g.A[z];
#pragma unroll
      for (int i = 0; i < 2; ++i) {
        const int c = wave * 2 + i;
        const unsigned short* gp = Ab + (size_t)(m0 + c * 16 + srow) * K + (k0 + scol);
        g2l16(gp, (void*)&lA[c * 512]);
      }
    }
    __syncthreads();
    short8 af[4], bfr[4];
#pragma unroll
    for (int mt = 0; mt < 4; ++mt)
      af[mt] = *(const short8*)&lA[(wm * 64 + mt * 16 + (lane & 15)) * 32 + (lane >> 4) * 8];
#pragma unroll
    for (int nt = 0; nt < 4; ++nt)
      bfr[nt] = *(const short8*)&lB[(wn * 64 + nt * 16 + (lane & 15)) * 32 + (lane >> 4) * 8];
#pragma unroll
    for (int mt = 0; mt < 4; ++mt)
#pragma unroll
      for (int nt = 0; nt < 4; ++nt)
        acc[mt][nt] = __builtin_amdgcn_mfma_f32_16x16x32_bf16(af[mt], bfr[nt], acc[mt][nt], 0, 0, 0);
  }

  // epilogue: C/D layout col=lane&15, row=(lane>>4)*4+reg
#pragma unroll
  for (int nt = 0; nt < 4; ++nt) {
    const int colg = n0 + wn * 64 + nt * 16 + (lane & 15);
    const float bv = bias[colg];
#pragma unroll
    for (int mt = 0; mt < 4; ++mt) {
#pragma unroll
      for (int r = 0; r < 4; ++r) {
        const int rowg = m0 + wm * 64 + mt * 16 + (lane >> 4) * 4 + r;
        float v = acc[mt][nt][r] + bv;
        if (act) v = (v > 0.f) ? (v + 1.f) : __expf(v);   // elu(x)+1
        C[(size_t)rowg * N + colg] = f2bf(v);
      }
    }
  }
}

// ---------------- q_sum[bh][d] = sum_n Q[b,n,h*64+d] ----------------
__global__ __launch_bounds__(256) void qsum_kernel(const unsigned short* Qp, float* qsum) {
  const int bh = blockIdx.x, b = bh >> 4, h = bh & 15;
  const int t = threadIdx.x, d = t & 63, gp = t >> 6;
  const unsigned short* base = Qp + (size_t)b * 4096 * 1024 + h * 64 + d;
  float s = 0.f;
  for (int n = gp; n < 4096; n += 4) s += bf2f(base[(size_t)n * 1024]);
  __shared__ float red[256];
  red[t] = s;
  __syncthreads();
  if (t < 64) qsum[bh * 64 + t] = red[t] + red[t + 64] + red[t + 128] + red[t + 192];
}

// ---------------- KtQ[bh][d][e] = sum_n K[n,d]*Q[n,e]; stores transposed (KtQ)^T[e][d] bf16 ----
#define KTS 136  // LDS row stride (ushorts): 272B = 16B-aligned, spreads frag-read banks
__global__ __launch_bounds__(256) void ktq_kernel(const unsigned short* Qp,
                                                  const unsigned short* Kp,
                                                  unsigned short* ktqt) {
  const int bh = blockIdx.x, b = bh >> 4, h = bh & 15;
  const unsigned short* Qh = Qp + (size_t)b * 4096 * 1024 + h * 64;
  const unsigned short* Kh = Kp + (size_t)b * 4096 * 1024 + h * 64;
  __shared__ unsigned short Kt[64 * KTS];
  __shared__ unsigned short Qt[64 * KTS];
  const int t = threadIdx.x, lane = t & 63, wave = t >> 6;
  floatx4 acc[4] = {};
  const int nlb = t >> 3;            // 0..31
  const int dblk = (t & 7) * 8;

  for (int c0 = 0; c0 < 4096; c0 += 128) {
    __syncthreads();
#pragma unroll
    for (int it = 0; it < 4; ++it) {
      const int nl = it * 32 + nlb;
      const size_t goff = (size_t)(c0 + nl) * 1024 + dblk;
      short8 kv = *(const short8*)(Kh + goff);
      short8 qv = *(const short8*)(Qh + goff);
#pragma unroll
      for (int j = 0; j < 8; ++j) {
        Kt[(dblk + j) * KTS + nl] = (unsigned short)kv[j];
        Qt[(dblk + j) * KTS + nl] = (unsigned short)qv[j];
      }
    }
    __syncthreads();
#pragma unroll
    for (int ks = 0; ks < 4; ++ks) {
      const short8 a = *(const short8*)&Kt[(wave * 16 + (lane & 15)) * KTS + ks * 32 + (lane >> 4) * 8];
#pragma unroll
      for (int et = 0; et < 4; ++et) {
        const short8 bb = *(const short8*)&Qt[(et * 16 + (lane & 15)) * KTS + ks * 32 + (lane >> 4) * 8];
        acc[et] = __builtin_amdgcn_mfma_f32_16x16x32_bf16(a, bb, acc[et], 0, 0, 0);
      }
    }
  }
  unsigned short* outp = ktqt + (size_t)bh * 4096;
#pragma unroll
  for (int et = 0; et < 4; ++et) {
    const int e = et * 16 + (lane & 15);
#pragma unroll
    for (int r = 0; r < 4; ++r) {
      const int d = wave * 16 + (lane >> 4) * 4 + r;
      outp[e * 64 + d] = f2bf(acc[et][r]);   // transposed store: [e][d]
    }
  }
}

// ---------------- U[b,n,h*64+e] = (sum_d V[n,d]*KtQ[d,e]) / (K[n,:].q_sum + eps) ----------------
#define CTS 72  // kt_lds row stride: 144B = 16B-aligned, bank-spread
__global__ __launch_bounds__(256) void stagec_kernel(const unsigned short* Kp,
                                                     const unsigned short* Vp,
                                                     const unsigned short* ktqt,
                                                     const float* qsum,
                                                     unsigned short* U) {
  const int bh = blockIdx.y, b = bh >> 4, h = bh & 15;
  const int n0 = blockIdx.x * 256;
  __shared__ unsigned short kt_lds[64 * CTS];
  __shared__ float qs[64];
  __shared__ float zbuf[256];
  const int t = threadIdx.x, lane = t & 63, wave = t >> 6;

  {
    const unsigned short* src = ktqt + (size_t)bh * 4096;
    const int row = t >> 2, seg = (t & 3) * 16;
    *(short8*)&kt_lds[row * CTS + seg] = *(const short8*)(src + row * 64 + seg);
    *(short8*)&kt_lds[row * CTS + seg + 8] = *(const short8*)(src + row * 64 + seg + 8);
  }
  if (t < 64) qs[t] = qsum[bh * 64 + t];
  __syncthreads();
  {
    const unsigned short* krow = Kp + ((size_t)b * 4096 + n0 + t) * 1024 + h * 64;
    float zv = 0.f;
#pragma unroll
    for (int j0 = 0; j0 < 64; j0 += 8) {
      short8 kv = *(const short8*)(krow + j0);
#pragma unroll
      for (int j = 0; j < 8; ++j) zv += bf2f((unsigned short)kv[j]) * qs[j0 + j];
    }
    zbuf[t] = zv;
  }
  __syncthreads();

  const unsigned short* Vh = Vp + (size_t)b * 4096 * 1024 + h * 64;
  floatx4 acc[4][4] = {};
#pragma unroll
  for (int ks = 0; ks < 2; ++ks) {
    short8 bfr[4];
#pragma unroll
    for (int et = 0; et < 4; ++et)
      bfr[et] = *(const short8*)&kt_lds[(et * 16 + (lane & 15)) * CTS + ks * 32 + (lane >> 4) * 8];
#pragma unroll
    for (int mt = 0; mt < 4; ++mt) {
      const short8 a = *(const short8*)(Vh + (size_t)(n0 + wave * 64 + mt * 16 + (lane & 15)) * 1024 +
                                        ks * 32 + (lane >> 4) * 8);
#pragma unroll
      for (int et = 0; et < 4; ++et)
        acc[mt][et] = __builtin_amdgcn_mfma_f32_16x16x32_bf16(a, bfr[et], acc[mt][et], 0, 0, 0);
    }
  }
#pragma unroll
  for (int mt = 0; mt < 4; ++mt) {
#pragma unroll
    for (int r = 0; r < 4; ++r) {
      const int rl = wave * 64 + mt * 16 + (lane >> 4) * 4 + r;
      const float inv = 1.0f / (zbuf[rl] + 1e-9f);
#pragma unroll
      for (int et = 0; et < 4; ++et) {
        const int e = et * 16 + (lane & 15);
        U[((size_t)b * 4096 + n0 + rl) * 1024 + h * 64 + e] = f2bf(acc[mt][et][r] * inv);
      }
    }
  }
}

// ---------------- residual + LayerNorm ----------------
__global__ __launch_bounds__(256) void ln_kernel(const float* query, const unsigned short* attn,
                                                 const float* gamma, const float* beta, float* out) {
  const int row = blockIdx.x, t = threadIdx.x;
  const float* qrow = query + (size_t)row * 1024;
  const unsigned short* arow = attn + (size_t)row * 1024;
  const float4 qv = *(const float4*)(qrow + t * 4);
  const ushortx4 av = *(const ushortx4*)(arow + t * 4);
  float x0 = qv.x + bf2f(av.x), x1 = qv.y + bf2f(av.y);
  float x2 = qv.z + bf2f(av.z), x3 = qv.w + bf2f(av.w);
  float s = x0 + x1 + x2 + x3;
  float s2 = x0 * x0 + x1 * x1 + x2 * x2 + x3 * x3;
  for (int off = 32; off > 0; off >>= 1) {
    s += __shfl_down(s, off);
    s2 += __shfl_down(s2, off);
  }
  __shared__ float lred[8];
  if ((t & 63) == 0) { lred[(t >> 6) * 2] = s; lred[(t >> 6) * 2 + 1] = s2; }
  __syncthreads();
  s = lred[0] + lred[2] + lred[4] + lred[6];
  s2 = lred[1] + lred[3] + lred[5] + lred[7];
  const float mu = s * (1.f / 1024.f);
  const float var = s2 * (1.f / 1024.f) - mu * mu;
  const float rstd = rsqrtf(var + 1e-6f);
  float4 o;
  o.x = (x0 - mu) * rstd * gamma[t * 4 + 0] + beta[t * 4 + 0];
  o.y = (x1 - mu) * rstd * gamma[t * 4 + 1] + beta[t * 4 + 1];
  o.z = (x2 - mu) * rstd * gamma[t * 4 + 2] + beta[t * 4 + 2];
  o.w = (x3 - mu) * rstd * gamma[t * 4 + 3] + beta[t * 4 + 3];
  *(float4*)(out + (size_t)row * 1024 + t * 4) = o;
}

// ---------------- launch ----------------
extern "C" void kernel_launch(void* const* d_in, const int* in_sizes, int n_in,
                              void* d_out, int out_size, void* d_ws, size_t ws_size,
                              hipStream_t stream) {
  const float* query = (const float*)d_in[0];
  const float* key_  = (const float*)d_in[1];
  const float* value = (const float*)d_in[2];
  const float* Wq = (const float*)d_in[3];
  const float* bq = (const float*)d_in[4];
  const float* Wk = (const float*)d_in[5];
  const float* bk = (const float*)d_in[6];
  const float* Wv = (const float*)d_in[7];
  const float* bv = (const float*)d_in[8];
  const float* Wo = (const float*)d_in[9];
  const float* bo = (const float*)d_in[10];
  const float* gamma = (const float*)d_in[11];
  const float* beta = (const float*)d_in[12];
  float* out = (float*)d_out;

  char* ws = (char*)d_ws;
  // ws layout (needs ~136.5 MiB): Qp/Kp/Vp/U bf16 (33.5MB each), WT bf16 (8MB), qsum, ktqt
  unsigned short* Qp = (unsigned short*)(ws + 0);
  unsigned short* Kp = (unsigned short*)(ws + 33554432);
  unsigned short* Vp = (unsigned short*)(ws + 67108864);
  unsigned short* U  = (unsigned short*)(ws + 100663296);
  unsigned short* WT = (unsigned short*)(ws + 134217728);
  float* qsumP = (float*)(ws + 134217728 + 8388608);
  unsigned short* ktqtP = (unsigned short*)(ws + 134217728 + 8388608 + 16384);
  unsigned short* attn = Qp;  // alias: Qp dead after ktq/qsum

  dim3 blk(256);

  W4 w4; w4.w[0] = Wq; w4.w[1] = Wk; w4.w[2] = Wv; w4.w[3] = Wo;
  wtrans_kernel<<<dim3(32, 32, 4), blk, 0, stream>>>(w4, WT);

  GArgs gq;
  gq.A[0] = query; gq.A[1] = key_; gq.A[2] = value;
  gq.BT[0] = WT; gq.BT[1] = WT + 1024 * 1024; gq.BT[2] = WT + 2 * 1024 * 1024;
  gq.bias[0] = bq; gq.bias[1] = bk; gq.bias[2] = bv;
  gq.C[0] = Qp; gq.C[1] = Kp; gq.C[2] = Vp;
  gq.act[0] = 1; gq.act[1] = 1; gq.act[2] = 0;
  gemm_bt_kernel<true><<<dim3(8, 128, 3), blk, 0, stream>>>(gq, 16384, 1024, 1024);

  qsum_kernel<<<64, blk, 0, stream>>>(Qp, qsumP);
  ktq_kernel<<<64, blk, 0, stream>>>(Qp, Kp, ktqtP);
  stagec_kernel<<<dim3(16, 64), blk, 0, stream>>>(Kp, Vp, ktqtP, qsumP, U);

  GArgs go;
  go.A[0] = U; go.A[1] = U; go.A[2] = U;
  go.BT[0] = WT + 3 * 1024 * 1024; go.BT[1] = go.BT[0]; go.BT[2] = go.BT[0];
  go.bias[0] = bo; go.bias[1] = bo; go.bias[2] = bo;
  go.C[0] = attn; go.C[1] = attn; go.C[2] = attn;
  go.act[0] = 0; go.act[1] = 0; go.act[2] = 0;
  gemm_bt_kernel<false><<<dim3(8, 128, 1), blk, 0, stream>>>(go, 16384, 1024, 1024);

  ln_kernel<<<16384, blk, 0, stream>>>(query, attn, gamma, beta, out);
}

// Round 2
// 681.745 us; speedup vs baseline: 1.4666x; 1.4666x over previous
//
#include <hip/hip_runtime.h>
#include <hip/hip_bf16.h>

// Problem: B=4, N=4096, D_MODEL=1024, H=16, DEPTH=64 (linear attention + LN)
// Pipeline: wtrans -> gemm(QKV, elu+1 on Q/K, fused q_sum) -> ktq -> stagec -> gemm(Wo) -> LN
// R1: fused q_sum into QKV GEMM epilogue (standalone qsum_kernel was 380us @ 44GB/s,
//     strided 2B reads, 2.8% occupancy).

typedef __attribute__((ext_vector_type(8))) short short8;
typedef __attribute__((ext_vector_type(4))) float floatx4;
typedef __attribute__((ext_vector_type(4))) unsigned short ushortx4;

#define DEVINL __device__ __forceinline__

DEVINL unsigned short f2bf(float f) {
  unsigned int u = __builtin_bit_cast(unsigned int, f);
  u += 0x7fffu + ((u >> 16) & 1u);            // RNE
  return (unsigned short)(u >> 16);
}
DEVINL float bf2f(unsigned short h) {
  unsigned int u = ((unsigned int)h) << 16;
  return __builtin_bit_cast(float, u);
}
// async global->LDS, 16B per lane; LDS dest = wave-uniform base + lane*16
DEVINL void g2l16(const void* g, void* l) {
  __builtin_amdgcn_global_load_lds((const __attribute__((address_space(1))) void*)g,
                                   (__attribute__((address_space(3))) void*)l, 16, 0, 0);
}

// ---------------- weight transpose + fp32->bf16 ----------------
struct W4 { const float* w[4]; };

__global__ __launch_bounds__(256) void wtrans_kernel(W4 wp, unsigned short* wt) {
  const int z = blockIdx.z;
  const float* W = wp.w[z];
  unsigned short* WT = wt + (size_t)z * 1024 * 1024;
  __shared__ float tile[32][33];
  const int bx = blockIdx.x, by = blockIdx.y;
  const int t = threadIdx.x, r = t >> 5, c = t & 31;
#pragma unroll
  for (int p = 0; p < 4; ++p)
    tile[p * 8 + r][c] = W[(size_t)(by * 32 + p * 8 + r) * 1024 + bx * 32 + c];
  __syncthreads();
#pragma unroll
  for (int p = 0; p < 4; ++p)
    WT[(size_t)(bx * 32 + p * 8 + r) * 1024 + by * 32 + c] = f2bf(tile[c][p * 8 + r]);
}

// ---------------- main GEMM: C[M,N] = A[M,K] * BT[N,K]^T + bias (opt elu+1, opt col-sum) ----
struct GArgs {
  const void* A[3];
  const unsigned short* BT[3];
  const float* bias[3];
  unsigned short* C[3];
  int act[3];
  int qs[3];        // fuse column-sum (q_sum) into epilogue
  float* qsum;      // [B*H, 64] fp32, must be zeroed before launch
};

template <bool AF32>
__global__ __launch_bounds__(256) void gemm_bt_kernel(GArgs g, int M, int N, int K) {
  const int z = blockIdx.z;
  const unsigned short* BT = g.BT[z];
  const float* bias = g.bias[z];
  unsigned short* C = g.C[z];
  const int act = g.act[z];
  const int qsflag = g.qs[z];

  const int n0 = blockIdx.x * 128;
  const int m0 = blockIdx.y * 128;
  __shared__ unsigned short lA[128 * 32];
  __shared__ unsigned short lB[128 * 32];
  const int t = threadIdx.x, lane = t & 63, wave = t >> 6;
  const int wm = wave >> 1, wn = wave & 1;

  floatx4 acc[4][4] = {};

  const int srow = lane >> 2;        // row-in-chunk for g2l staging
  const int scol = (lane & 3) * 8;   // elem col

  for (int k0 = 0; k0 < K; k0 += 32) {
    __syncthreads();
    // stage B tile (bf16) via global_load_lds: 8 chunks of 16 rows, 2 per wave
#pragma unroll
    for (int i = 0; i < 2; ++i) {
      const int c = wave * 2 + i;
      const unsigned short* gp = BT + (size_t)(n0 + c * 16 + srow) * K + (k0 + scol);
      g2l16(gp, (void*)&lB[c * 512]);
    }
    if constexpr (AF32) {
      // A is fp32 in global: load float4, convert, ds_write bf16x4
      const float* Af = (const float*)g.A[z];
#pragma unroll
      for (int i = 0; i < 4; ++i) {
        const int e = i * 1024 + t * 4;
        const int row = e >> 5, col = e & 31;
        const float4 v = *(const float4*)(Af + (size_t)(m0 + row) * K + (k0 + col));
        ushortx4 hv;
        hv.x = f2bf(v.x); hv.y = f2bf(v.y); hv.z = f2bf(v.z); hv.w = f2bf(v.w);
        *(ushortx4*)&lA[row * 32 + col] = hv;
      }
    } else {
      const unsigned short* Ab = (const unsigned short*)g.A[z];
#pragma unroll
      for (int i = 0; i < 2; ++i) {
        const int c = wave * 2 + i;
        const unsigned short* gp = Ab + (size_t)(m0 + c * 16 + srow) * K + (k0 + scol);
        g2l16(gp, (void*)&lA[c * 512]);
      }
    }
    __syncthreads();
    short8 af[4], bfr[4];
#pragma unroll
    for (int mt = 0; mt < 4; ++mt)
      af[mt] = *(const short8*)&lA[(wm * 64 + mt * 16 + (lane & 15)) * 32 + (lane >> 4) * 8];
#pragma unroll
    for (int nt = 0; nt < 4; ++nt)
      bfr[nt] = *(const short8*)&lB[(wn * 64 + nt * 16 + (lane & 15)) * 32 + (lane >> 4) * 8];
#pragma unroll
    for (int mt = 0; mt < 4; ++mt)
#pragma unroll
      for (int nt = 0; nt < 4; ++nt)
        acc[mt][nt] = __builtin_amdgcn_mfma_f32_16x16x32_bf16(af[mt], bfr[nt], acc[mt][nt], 0, 0, 0);
  }

  // epilogue: C/D layout col=lane&15, row=(lane>>4)*4+reg
  float cs[4] = {0.f, 0.f, 0.f, 0.f};   // per-lane column partial sums (16 rows each)
#pragma unroll
  for (int nt = 0; nt < 4; ++nt) {
    const int colg = n0 + wn * 64 + nt * 16 + (lane & 15);
    const float bv = bias[colg];
#pragma unroll
    for (int mt = 0; mt < 4; ++mt) {
#pragma unroll
      for (int r = 0; r < 4; ++r) {
        const int rowg = m0 + wm * 64 + mt * 16 + (lane >> 4) * 4 + r;
        float v = acc[mt][nt][r] + bv;
        if (act) v = (v > 0.f) ? (v + 1.f) : __expf(v);   // elu(x)+1
        cs[nt] += v;
        C[(size_t)rowg * N + colg] = f2bf(v);
      }
    }
  }
  if (qsflag) {
    const int b = m0 >> 12;   // 128-row tiles never straddle a batch (4096 % 128 == 0)
#pragma unroll
    for (int nt = 0; nt < 4; ++nt) {
      float v = cs[nt];
      v += __shfl_xor(v, 16);
      v += __shfl_xor(v, 32);   // lanes 0..15 now hold the full 64-row column sum of this wave
      if (lane < 16) {
        const int colg = n0 + wn * 64 + nt * 16 + lane;
        atomicAdd(&g.qsum[(b * 16 + (colg >> 6)) * 64 + (colg & 63)], v);
      }
    }
  }
}

// ---------------- KtQ[bh][d][e] = sum_n K[n,d]*Q[n,e]; stores transposed (KtQ)^T[e][d] bf16 ----
#define KTS 136  // LDS row stride (ushorts): 272B = 16B-aligned, spreads frag-read banks
__global__ __launch_bounds__(256) void ktq_kernel(const unsigned short* Qp,
                                                  const unsigned short* Kp,
                                                  unsigned short* ktqt) {
  const int bh = blockIdx.x, b = bh >> 4, h = bh & 15;
  const unsigned short* Qh = Qp + (size_t)b * 4096 * 1024 + h * 64;
  const unsigned short* Kh = Kp + (size_t)b * 4096 * 1024 + h * 64;
  __shared__ unsigned short Kt[64 * KTS];
  __shared__ unsigned short Qt[64 * KTS];
  const int t = threadIdx.x, lane = t & 63, wave = t >> 6;
  floatx4 acc[4] = {};
  const int nlb = t >> 3;            // 0..31
  const int dblk = (t & 7) * 8;

  for (int c0 = 0; c0 < 4096; c0 += 128) {
    __syncthreads();
#pragma unroll
    for (int it = 0; it < 4; ++it) {
      const int nl = it * 32 + nlb;
      const size_t goff = (size_t)(c0 + nl) * 1024 + dblk;
      short8 kv = *(const short8*)(Kh + goff);
      short8 qv = *(const short8*)(Qh + goff);
#pragma unroll
      for (int j = 0; j < 8; ++j) {
        Kt[(dblk + j) * KTS + nl] = (unsigned short)kv[j];
        Qt[(dblk + j) * KTS + nl] = (unsigned short)qv[j];
      }
    }
    __syncthreads();
#pragma unroll
    for (int ks = 0; ks < 4; ++ks) {
      const short8 a = *(const short8*)&Kt[(wave * 16 + (lane & 15)) * KTS + ks * 32 + (lane >> 4) * 8];
#pragma unroll
      for (int et = 0; et < 4; ++et) {
        const short8 bb = *(const short8*)&Qt[(et * 16 + (lane & 15)) * KTS + ks * 32 + (lane >> 4) * 8];
        acc[et] = __builtin_amdgcn_mfma_f32_16x16x32_bf16(a, bb, acc[et], 0, 0, 0);
      }
    }
  }
  unsigned short* outp = ktqt + (size_t)bh * 4096;
#pragma unroll
  for (int et = 0; et < 4; ++et) {
    const int e = et * 16 + (lane & 15);
#pragma unroll
    for (int r = 0; r < 4; ++r) {
      const int d = wave * 16 + (lane >> 4) * 4 + r;
      outp[e * 64 + d] = f2bf(acc[et][r]);   // transposed store: [e][d]
    }
  }
}

// ---------------- U[b,n,h*64+e] = (sum_d V[n,d]*KtQ[d,e]) / (K[n,:].q_sum + eps) ----------------
#define CTS 72  // kt_lds row stride: 144B = 16B-aligned, bank-spread
__global__ __launch_bounds__(256) void stagec_kernel(const unsigned short* Kp,
                                                     const unsigned short* Vp,
                                                     const unsigned short* ktqt,
                                                     const float* qsum,
                                                     unsigned short* U) {
  const int bh = blockIdx.y, b = bh >> 4, h = bh & 15;
  const int n0 = blockIdx.x * 256;
  __shared__ unsigned short kt_lds[64 * CTS];
  __shared__ float qs[64];
  __shared__ float zbuf[256];
  const int t = threadIdx.x, lane = t & 63, wave = t >> 6;

  {
    const unsigned short* src = ktqt + (size_t)bh * 4096;
    const int row = t >> 2, seg = (t & 3) * 16;
    *(short8*)&kt_lds[row * CTS + seg] = *(const short8*)(src + row * 64 + seg);
    *(short8*)&kt_lds[row * CTS + seg + 8] = *(const short8*)(src + row * 64 + seg + 8);
  }
  if (t < 64) qs[t] = qsum[bh * 64 + t];
  __syncthreads();
  {
    const unsigned short* krow = Kp + ((size_t)b * 4096 + n0 + t) * 1024 + h * 64;
    float zv = 0.f;
#pragma unroll
    for (int j0 = 0; j0 < 64; j0 += 8) {
      short8 kv = *(const short8*)(krow + j0);
#pragma unroll
      for (int j = 0; j < 8; ++j) zv += bf2f((unsigned short)kv[j]) * qs[j0 + j];
    }
    zbuf[t] = zv;
  }
  __syncthreads();

  const unsigned short* Vh = Vp + (size_t)b * 4096 * 1024 + h * 64;
  floatx4 acc[4][4] = {};
#pragma unroll
  for (int ks = 0; ks < 2; ++ks) {
    short8 bfr[4];
#pragma unroll
    for (int et = 0; et < 4; ++et)
      bfr[et] = *(const short8*)&kt_lds[(et * 16 + (lane & 15)) * CTS + ks * 32 + (lane >> 4) * 8];
#pragma unroll
    for (int mt = 0; mt < 4; ++mt) {
      const short8 a = *(const short8*)(Vh + (size_t)(n0 + wave * 64 + mt * 16 + (lane & 15)) * 1024 +
                                        ks * 32 + (lane >> 4) * 8);
#pragma unroll
      for (int et = 0; et < 4; ++et)
        acc[mt][et] = __builtin_amdgcn_mfma_f32_16x16x32_bf16(a, bfr[et], acc[mt][et], 0, 0, 0);
    }
  }
#pragma unroll
  for (int mt = 0; mt < 4; ++mt) {
#pragma unroll
    for (int r = 0; r < 4; ++r) {
      const int rl = wave * 64 + mt * 16 + (lane >> 4) * 4 + r;
      const float inv = 1.0f / (zbuf[rl] + 1e-9f);
#pragma unroll
      for (int et = 0; et < 4; ++et) {
        const int e = et * 16 + (lane & 15);
        U[((size_t)b * 4096 + n0 + rl) * 1024 + h * 64 + e] = f2bf(acc[mt][et][r] * inv);
      }
    }
  }
}

// ---------------- residual + LayerNorm ----------------
__global__ __launch_bounds__(256) void ln_kernel(const float* query, const unsigned short* attn,
                                                 const float* gamma, const float* beta, float* out) {
  const int row = blockIdx.x, t = threadIdx.x;
  const float* qrow = query + (size_t)row * 1024;
  const unsigned short* arow = attn + (size_t)row * 1024;
  const float4 qv = *(const float4*)(qrow + t * 4);
  const ushortx4 av = *(const ushortx4*)(arow + t * 4);
  float x0 = qv.x + bf2f(av.x), x1 = qv.y + bf2f(av.y);
  float x2 = qv.z + bf2f(av.z), x3 = qv.w + bf2f(av.w);
  float s = x0 + x1 + x2 + x3;
  float s2 = x0 * x0 + x1 * x1 + x2 * x2 + x3 * x3;
  for (int off = 32; off > 0; off >>= 1) {
    s += __shfl_down(s, off);
    s2 += __shfl_down(s2, off);
  }
  __shared__ float lred[8];
  if ((t & 63) == 0) { lred[(t >> 6) * 2] = s; lred[(t >> 6) * 2 + 1] = s2; }
  __syncthreads();
  s = lred[0] + lred[2] + lred[4] + lred[6];
  s2 = lred[1] + lred[3] + lred[5] + lred[7];
  const float mu = s * (1.f / 1024.f);
  const float var = s2 * (1.f / 1024.f) - mu * mu;
  const float rstd = rsqrtf(var + 1e-6f);
  float4 o;
  o.x = (x0 - mu) * rstd * gamma[t * 4 + 0] + beta[t * 4 + 0];
  o.y = (x1 - mu) * rstd * gamma[t * 4 + 1] + beta[t * 4 + 1];
  o.z = (x2 - mu) * rstd * gamma[t * 4 + 2] + beta[t * 4 + 2];
  o.w = (x3 - mu) * rstd * gamma[t * 4 + 3] + beta[t * 4 + 3];
  *(float4*)(out + (size_t)row * 1024 + t * 4) = o;
}

// ---------------- launch ----------------
extern "C" void kernel_launch(void* const* d_in, const int* in_sizes, int n_in,
                              void* d_out, int out_size, void* d_ws, size_t ws_size,
                              hipStream_t stream) {
  const float* query = (const float*)d_in[0];
  const float* key_  = (const float*)d_in[1];
  const float* value = (const float*)d_in[2];
  const float* Wq = (const float*)d_in[3];
  const float* bq = (const float*)d_in[4];
  const float* Wk = (const float*)d_in[5];
  const float* bk = (const float*)d_in[6];
  const float* Wv = (const float*)d_in[7];
  const float* bv = (const float*)d_in[8];
  const float* Wo = (const float*)d_in[9];
  const float* bo = (const float*)d_in[10];
  const float* gamma = (const float*)d_in[11];
  const float* beta = (const float*)d_in[12];
  float* out = (float*)d_out;

  char* ws = (char*)d_ws;
  // ws layout (needs ~136.5 MiB): Qp/Kp/Vp/U bf16 (33.5MB each), WT bf16 (8MB), qsum, ktqt
  unsigned short* Qp = (unsigned short*)(ws + 0);
  unsigned short* Kp = (unsigned short*)(ws + 33554432);
  unsigned short* Vp = (unsigned short*)(ws + 67108864);
  unsigned short* U  = (unsigned short*)(ws + 100663296);
  unsigned short* WT = (unsigned short*)(ws + 134217728);
  float* qsumP = (float*)(ws + 134217728 + 8388608);
  unsigned short* ktqtP = (unsigned short*)(ws + 134217728 + 8388608 + 16384);
  unsigned short* attn = Qp;  // alias: Qp dead after ktq

  dim3 blk(256);

  W4 w4; w4.w[0] = Wq; w4.w[1] = Wk; w4.w[2] = Wv; w4.w[3] = Wo;
  wtrans_kernel<<<dim3(32, 32, 4), blk, 0, stream>>>(w4, WT);

  // zero the fused q_sum accumulator (16 KB)
  hipMemsetAsync(qsumP, 0, 64 * 64 * sizeof(float), stream);

  GArgs gq;
  gq.A[0] = query; gq.A[1] = key_; gq.A[2] = value;
  gq.BT[0] = WT; gq.BT[1] = WT + 1024 * 1024; gq.BT[2] = WT + 2 * 1024 * 1024;
  gq.bias[0] = bq; gq.bias[1] = bk; gq.bias[2] = bv;
  gq.C[0] = Qp; gq.C[1] = Kp; gq.C[2] = Vp;
  gq.act[0] = 1; gq.act[1] = 1; gq.act[2] = 0;
  gq.qs[0] = 1; gq.qs[1] = 0; gq.qs[2] = 0;
  gq.qsum = qsumP;
  gemm_bt_kernel<true><<<dim3(8, 128, 3), blk, 0, stream>>>(gq, 16384, 1024, 1024);

  ktq_kernel<<<64, blk, 0, stream>>>(Qp, Kp, ktqtP);
  stagec_kernel<<<dim3(16, 64), blk, 0, stream>>>(Kp, Vp, ktqtP, qsumP, U);

  GArgs go;
  go.A[0] = U; go.A[1] = U; go.A[2] = U;
  go.BT[0] = WT + 3 * 1024 * 1024; go.BT[1] = go.BT[0]; go.BT[2] = go.BT[0];
  go.bias[0] = bo; go.bias[1] = bo; go.bias[2] = bo;
  go.C[0] = attn; go.C[1] = attn; go.C[2] = attn;
  go.act[0] = 0; go.act[1] = 0; go.act[2] = 0;
  go.qs[0] = 0; go.qs[1] = 0; go.qs[2] = 0;
  go.qsum = qsumP;
  gemm_bt_kernel<false><<<dim3(8, 128, 1), blk, 0, stream>>>(go, 16384, 1024, 1024);

  ln_kernel<<<16384, blk, 0, stream>>>(query, attn, gamma, beta, out);
}

// Round 3
// 653.646 us; speedup vs baseline: 1.5296x; 1.0430x over previous
//
#include <hip/hip_runtime.h>
#include <hip/hip_bf16.h>

// Problem: B=4, N=4096, D_MODEL=1024, H=16, DEPTH=64 (linear attention + LN)
// Pipeline: wtrans -> [conv->gemm]x3 (QKV, elu+1 on Q/K, fused q_sum) -> ktq -> stagec
//           -> gemm(Wo) -> LN
// R1: fused q_sum into QKV GEMM epilogue (was 380us standalone).
// R2: fp32->bf16 conv pass + pure-bf16 GEMM (global_load_lds both operands); the fused
//     fp32-A staging path ran at 320 TF (MfmaUtil 13%, VALUBusy 30%). XCD swizzle
//     (m-fastest id) so the 8 n-blocks sharing an A row-panel land on one XCD.

typedef __attribute__((ext_vector_type(8))) short short8;
typedef __attribute__((ext_vector_type(4))) float floatx4;
typedef __attribute__((ext_vector_type(4))) unsigned short ushortx4;
typedef __attribute__((ext_vector_type(8))) unsigned short ushortx8;

#define DEVINL __device__ __forceinline__

DEVINL unsigned short f2bf(float f) {
  unsigned int u = __builtin_bit_cast(unsigned int, f);
  u += 0x7fffu + ((u >> 16) & 1u);            // RNE
  return (unsigned short)(u >> 16);
}
DEVINL float bf2f(unsigned short h) {
  unsigned int u = ((unsigned int)h) << 16;
  return __builtin_bit_cast(float, u);
}
// async global->LDS, 16B per lane; LDS dest = wave-uniform base + lane*16
DEVINL void g2l16(const void* g, void* l) {
  __builtin_amdgcn_global_load_lds((const __attribute__((address_space(1))) void*)g,
                                   (__attribute__((address_space(3))) void*)l, 16, 0, 0);
}

// ---------------- fp32 -> bf16 elementwise (memory-bound) ----------------
__global__ __launch_bounds__(256) void conv_kernel(const float* __restrict__ in,
                                                   unsigned short* __restrict__ out) {
  const size_t i = ((size_t)blockIdx.x * 256 + threadIdx.x) * 8;
  const float4 a = *(const float4*)(in + i);
  const float4 b = *(const float4*)(in + i + 4);
  ushortx8 o;
  o[0] = f2bf(a.x); o[1] = f2bf(a.y); o[2] = f2bf(a.z); o[3] = f2bf(a.w);
  o[4] = f2bf(b.x); o[5] = f2bf(b.y); o[6] = f2bf(b.z); o[7] = f2bf(b.w);
  *(ushortx8*)(out + i) = o;
}

// ---------------- weight transpose + fp32->bf16 ----------------
struct W4 { const float* w[4]; };

__global__ __launch_bounds__(256) void wtrans_kernel(W4 wp, unsigned short* wt) {
  const int z = blockIdx.z;
  const float* W = wp.w[z];
  unsigned short* WT = wt + (size_t)z * 1024 * 1024;
  __shared__ float tile[32][33];
  const int bx = blockIdx.x, by = blockIdx.y;
  const int t = threadIdx.x, r = t >> 5, c = t & 31;
#pragma unroll
  for (int p = 0; p < 4; ++p)
    tile[p * 8 + r][c] = W[(size_t)(by * 32 + p * 8 + r) * 1024 + bx * 32 + c];
  __syncthreads();
#pragma unroll
  for (int p = 0; p < 4; ++p)
    WT[(size_t)(bx * 32 + p * 8 + r) * 1024 + by * 32 + c] = f2bf(tile[c][p * 8 + r]);
}

// ---------------- main GEMM: C[M,N] = A[M,K] * BT[N,K]^T + bias (opt elu+1, col-sum) ----
// grid = (M/128)*(N/128) 1D; m-fastest id => the 8 n-blocks sharing an A panel map to
// the same XCD (id%8 == m_idx%8 since M/128 % 8 == 0).
__global__ __launch_bounds__(256) void gemm_bt_kernel(const unsigned short* __restrict__ A,
                                                      const unsigned short* __restrict__ BT,
                                                      const float* __restrict__ bias,
                                                      unsigned short* __restrict__ C,
                                                      int act, int qsflag, float* qsum,
                                                      int M, int N, int K) {
  const int mb = M >> 7;
  const int id = blockIdx.x;
  const int m0 = (id % mb) * 128;
  const int n0 = (id / mb) * 128;
  __shared__ unsigned short lA[128 * 32];
  __shared__ unsigned short lB[128 * 32];
  const int t = threadIdx.x, lane = t & 63, wave = t >> 6;
  const int wm = wave >> 1, wn = wave & 1;

  floatx4 acc[4][4] = {};

  const int srow = lane >> 2;        // row-in-chunk for g2l staging
  const int scol = (lane & 3) * 8;   // elem col

  for (int k0 = 0; k0 < K; k0 += 32) {
    __syncthreads();
    // stage A and B tiles (bf16) via global_load_lds: 8 chunks of 16 rows each, 2/wave
#pragma unroll
    for (int i = 0; i < 2; ++i) {
      const int c = wave * 2 + i;
      g2l16(BT + (size_t)(n0 + c * 16 + srow) * K + (k0 + scol), (void*)&lB[c * 512]);
      g2l16(A + (size_t)(m0 + c * 16 + srow) * K + (k0 + scol), (void*)&lA[c * 512]);
    }
    __syncthreads();
    short8 af[4], bfr[4];
#pragma unroll
    for (int mt = 0; mt < 4; ++mt)
      af[mt] = *(const short8*)&lA[(wm * 64 + mt * 16 + (lane & 15)) * 32 + (lane >> 4) * 8];
#pragma unroll
    for (int nt = 0; nt < 4; ++nt)
      bfr[nt] = *(const short8*)&lB[(wn * 64 + nt * 16 + (lane & 15)) * 32 + (lane >> 4) * 8];
#pragma unroll
    for (int mt = 0; mt < 4; ++mt)
#pragma unroll
      for (int nt = 0; nt < 4; ++nt)
        acc[mt][nt] = __builtin_amdgcn_mfma_f32_16x16x32_bf16(af[mt], bfr[nt], acc[mt][nt], 0, 0, 0);
  }

  // epilogue: C/D layout col=lane&15, row=(lane>>4)*4+reg
  float cs[4] = {0.f, 0.f, 0.f, 0.f};   // per-lane column partial sums (16 rows each)
#pragma unroll
  for (int nt = 0; nt < 4; ++nt) {
    const int colg = n0 + wn * 64 + nt * 16 + (lane & 15);
    const float bv = bias[colg];
#pragma unroll
    for (int mt = 0; mt < 4; ++mt) {
#pragma unroll
      for (int r = 0; r < 4; ++r) {
        const int rowg = m0 + wm * 64 + mt * 16 + (lane >> 4) * 4 + r;
        float v = acc[mt][nt][r] + bv;
        if (act) v = (v > 0.f) ? (v + 1.f) : __expf(v);   // elu(x)+1
        cs[nt] += v;
        C[(size_t)rowg * N + colg] = f2bf(v);
      }
    }
  }
  if (qsflag) {
    const int b = m0 >> 12;   // 128-row tiles never straddle a batch (4096 % 128 == 0)
#pragma unroll
    for (int nt = 0; nt < 4; ++nt) {
      float v = cs[nt];
      v += __shfl_xor(v, 16);
      v += __shfl_xor(v, 32);   // lanes 0..15 now hold the full 64-row column sum of this wave
      if (lane < 16) {
        const int colg = n0 + wn * 64 + nt * 16 + lane;
        atomicAdd(&qsum[(b * 16 + (colg >> 6)) * 64 + (colg & 63)], v);
      }
    }
  }
}

// ---------------- KtQ[bh][d][e] = sum_n K[n,d]*Q[n,e]; stores transposed (KtQ)^T[e][d] bf16 ----
#define KTS 136  // LDS row stride (ushorts): 272B = 16B-aligned, spreads frag-read banks
__global__ __launch_bounds__(256) void ktq_kernel(const unsigned short* Qp,
                                                  const unsigned short* Kp,
                                                  unsigned short* ktqt) {
  const int bh = blockIdx.x, b = bh >> 4, h = bh & 15;
  const unsigned short* Qh = Qp + (size_t)b * 4096 * 1024 + h * 64;
  const unsigned short* Kh = Kp + (size_t)b * 4096 * 1024 + h * 64;
  __shared__ unsigned short Kt[64 * KTS];
  __shared__ unsigned short Qt[64 * KTS];
  const int t = threadIdx.x, lane = t & 63, wave = t >> 6;
  floatx4 acc[4] = {};
  const int nlb = t >> 3;            // 0..31
  const int dblk = (t & 7) * 8;

  for (int c0 = 0; c0 < 4096; c0 += 128) {
    __syncthreads();
#pragma unroll
    for (int it = 0; it < 4; ++it) {
      const int nl = it * 32 + nlb;
      const size_t goff = (size_t)(c0 + nl) * 1024 + dblk;
      short8 kv = *(const short8*)(Kh + goff);
      short8 qv = *(const short8*)(Qh + goff);
#pragma unroll
      for (int j = 0; j < 8; ++j) {
        Kt[(dblk + j) * KTS + nl] = (unsigned short)kv[j];
        Qt[(dblk + j) * KTS + nl] = (unsigned short)qv[j];
      }
    }
    __syncthreads();
#pragma unroll
    for (int ks = 0; ks < 4; ++ks) {
      const short8 a = *(const short8*)&Kt[(wave * 16 + (lane & 15)) * KTS + ks * 32 + (lane >> 4) * 8];
#pragma unroll
      for (int et = 0; et < 4; ++et) {
        const short8 bb = *(const short8*)&Qt[(et * 16 + (lane & 15)) * KTS + ks * 32 + (lane >> 4) * 8];
        acc[et] = __builtin_amdgcn_mfma_f32_16x16x32_bf16(a, bb, acc[et], 0, 0, 0);
      }
    }
  }
  unsigned short* outp = ktqt + (size_t)bh * 4096;
#pragma unroll
  for (int et = 0; et < 4; ++et) {
    const int e = et * 16 + (lane & 15);
#pragma unroll
    for (int r = 0; r < 4; ++r) {
      const int d = wave * 16 + (lane >> 4) * 4 + r;
      outp[e * 64 + d] = f2bf(acc[et][r]);   // transposed store: [e][d]
    }
  }
}

// ---------------- U[b,n,h*64+e] = (sum_d V[n,d]*KtQ[d,e]) / (K[n,:].q_sum + eps) ----------------
#define CTS 72  // kt_lds row stride: 144B = 16B-aligned, bank-spread
__global__ __launch_bounds__(256) void stagec_kernel(const unsigned short* Kp,
                                                     const unsigned short* Vp,
                                                     const unsigned short* ktqt,
                                                     const float* qsum,
                                                     unsigned short* U) {
  const int bh = blockIdx.y, b = bh >> 4, h = bh & 15;
  const int n0 = blockIdx.x * 256;
  __shared__ unsigned short kt_lds[64 * CTS];
  __shared__ float qs[64];
  __shared__ float zbuf[256];
  const int t = threadIdx.x, lane = t & 63, wave = t >> 6;

  {
    const unsigned short* src = ktqt + (size_t)bh * 4096;
    const int row = t >> 2, seg = (t & 3) * 16;
    *(short8*)&kt_lds[row * CTS + seg] = *(const short8*)(src + row * 64 + seg);
    *(short8*)&kt_lds[row * CTS + seg + 8] = *(const short8*)(src + row * 64 + seg + 8);
  }
  if (t < 64) qs[t] = qsum[bh * 64 + t];
  __syncthreads();
  {
    const unsigned short* krow = Kp + ((size_t)b * 4096 + n0 + t) * 1024 + h * 64;
    float zv = 0.f;
#pragma unroll
    for (int j0 = 0; j0 < 64; j0 += 8) {
      short8 kv = *(const short8*)(krow + j0);
#pragma unroll
      for (int j = 0; j < 8; ++j) zv += bf2f((unsigned short)kv[j]) * qs[j0 + j];
    }
    zbuf[t] = zv;
  }
  __syncthreads();

  const unsigned short* Vh = Vp + (size_t)b * 4096 * 1024 + h * 64;
  floatx4 acc[4][4] = {};
#pragma unroll
  for (int ks = 0; ks < 2; ++ks) {
    short8 bfr[4];
#pragma unroll
    for (int et = 0; et < 4; ++et)
      bfr[et] = *(const short8*)&kt_lds[(et * 16 + (lane & 15)) * CTS + ks * 32 + (lane >> 4) * 8];
#pragma unroll
    for (int mt = 0; mt < 4; ++mt) {
      const short8 a = *(const short8*)(Vh + (size_t)(n0 + wave * 64 + mt * 16 + (lane & 15)) * 1024 +
                                        ks * 32 + (lane >> 4) * 8);
#pragma unroll
      for (int et = 0; et < 4; ++et)
        acc[mt][et] = __builtin_amdgcn_mfma_f32_16x16x32_bf16(a, bfr[et], acc[mt][et], 0, 0, 0);
    }
  }
#pragma unroll
  for (int mt = 0; mt < 4; ++mt) {
#pragma unroll
    for (int r = 0; r < 4; ++r) {
      const int rl = wave * 64 + mt * 16 + (lane >> 4) * 4 + r;
      const float inv = 1.0f / (zbuf[rl] + 1e-9f);
#pragma unroll
      for (int et = 0; et < 4; ++et) {
        const int e = et * 16 + (lane & 15);
        U[((size_t)b * 4096 + n0 + rl) * 1024 + h * 64 + e] = f2bf(acc[mt][et][r] * inv);
      }
    }
  }
}

// ---------------- residual + LayerNorm ----------------
__global__ __launch_bounds__(256) void ln_kernel(const float* query, const unsigned short* attn,
                                                 const float* gamma, const float* beta, float* out) {
  const int row = blockIdx.x, t = threadIdx.x;
  const float* qrow = query + (size_t)row * 1024;
  const unsigned short* arow = attn + (size_t)row * 1024;
  const float4 qv = *(const float4*)(qrow + t * 4);
  const ushortx4 av = *(const ushortx4*)(arow + t * 4);
  float x0 = qv.x + bf2f(av.x), x1 = qv.y + bf2f(av.y);
  float x2 = qv.z + bf2f(av.z), x3 = qv.w + bf2f(av.w);
  float s = x0 + x1 + x2 + x3;
  float s2 = x0 * x0 + x1 * x1 + x2 * x2 + x3 * x3;
  for (int off = 32; off > 0; off >>= 1) {
    s += __shfl_down(s, off);
    s2 += __shfl_down(s2, off);
  }
  __shared__ float lred[8];
  if ((t & 63) == 0) { lred[(t >> 6) * 2] = s; lred[(t >> 6) * 2 + 1] = s2; }
  __syncthreads();
  s = lred[0] + lred[2] + lred[4] + lred[6];
  s2 = lred[1] + lred[3] + lred[5] + lred[7];
  const float mu = s * (1.f / 1024.f);
  const float var = s2 * (1.f / 1024.f) - mu * mu;
  const float rstd = rsqrtf(var + 1e-6f);
  float4 o;
  o.x = (x0 - mu) * rstd * gamma[t * 4 + 0] + beta[t * 4 + 0];
  o.y = (x1 - mu) * rstd * gamma[t * 4 + 1] + beta[t * 4 + 1];
  o.z = (x2 - mu) * rstd * gamma[t * 4 + 2] + beta[t * 4 + 2];
  o.w = (x3 - mu) * rstd * gamma[t * 4 + 3] + beta[t * 4 + 3];
  *(float4*)(out + (size_t)row * 1024 + t * 4) = o;
}

// ---------------- launch ----------------
extern "C" void kernel_launch(void* const* d_in, const int* in_sizes, int n_in,
                              void* d_out, int out_size, void* d_ws, size_t ws_size,
                              hipStream_t stream) {
  const float* query = (const float*)d_in[0];
  const float* key_  = (const float*)d_in[1];
  const float* value = (const float*)d_in[2];
  const float* Wq = (const float*)d_in[3];
  const float* bq = (const float*)d_in[4];
  const float* Wk = (const float*)d_in[5];
  const float* bk = (const float*)d_in[6];
  const float* Wv = (const float*)d_in[7];
  const float* bv = (const float*)d_in[8];
  const float* Wo = (const float*)d_in[9];
  const float* bo = (const float*)d_in[10];
  const float* gamma = (const float*)d_in[11];
  const float* beta = (const float*)d_in[12];
  float* out = (float*)d_out;

  char* ws = (char*)d_ws;
  // ws layout (~136.6 MiB peak, same footprint class as R1):
  //   abf (32MB, rotating bf16 A; aliased by U after QKV) | Qp | Kp | Vp | WT (8MB)
  //   | qsum (16KB) | ktqt (512KB).  attn aliases Qp (dead after ktq).
  unsigned short* abf = (unsigned short*)(ws + 0);
  unsigned short* Qp = (unsigned short*)(ws + 33554432);
  unsigned short* Kp = (unsigned short*)(ws + 67108864);
  unsigned short* Vp = (unsigned short*)(ws + 100663296);
  unsigned short* WT = (unsigned short*)(ws + 134217728);
  float* qsumP = (float*)(ws + 142606336);
  unsigned short* ktqtP = (unsigned short*)(ws + 142606336 + 16384);
  unsigned short* U = abf;     // abf dead after gemmV
  unsigned short* attn = Qp;   // Qp dead after ktq

  dim3 blk(256);

  W4 w4; w4.w[0] = Wq; w4.w[1] = Wk; w4.w[2] = Wv; w4.w[3] = Wo;
  wtrans_kernel<<<dim3(32, 32, 4), blk, 0, stream>>>(w4, WT);

  // zero the fused q_sum accumulator (16 KB)
  hipMemsetAsync(qsumP, 0, 64 * 64 * sizeof(float), stream);

  // 16384*1024 elems / (256 thr * 8 elems) = 8192 blocks
  const int convGrid = 8192;
  const int gemmGrid = 128 * 8;   // (M/128)*(N/128)

  conv_kernel<<<convGrid, blk, 0, stream>>>(query, abf);
  gemm_bt_kernel<<<gemmGrid, blk, 0, stream>>>(abf, WT, bq, Qp, 1, 1, qsumP, 16384, 1024, 1024);

  conv_kernel<<<convGrid, blk, 0, stream>>>(key_, abf);
  gemm_bt_kernel<<<gemmGrid, blk, 0, stream>>>(abf, WT + 1024 * 1024, bk, Kp, 1, 0, qsumP, 16384, 1024, 1024);

  conv_kernel<<<convGrid, blk, 0, stream>>>(value, abf);
  gemm_bt_kernel<<<gemmGrid, blk, 0, stream>>>(abf, WT + 2 * 1024 * 1024, bv, Vp, 0, 0, qsumP, 16384, 1024, 1024);

  ktq_kernel<<<64, blk, 0, stream>>>(Qp, Kp, ktqtP);
  stagec_kernel<<<dim3(16, 64), blk, 0, stream>>>(Kp, Vp, ktqtP, qsumP, U);

  gemm_bt_kernel<<<gemmGrid, blk, 0, stream>>>(U, WT + 3 * 1024 * 1024, bo, attn, 0, 0, qsumP, 16384, 1024, 1024);

  ln_kernel<<<16384, blk, 0, stream>>>(query, attn, gamma, beta, out);
}

// Round 4
// 614.113 us; speedup vs baseline: 1.6281x; 1.0644x over previous
//
#include <hip/hip_runtime.h>
#include <hip/hip_bf16.h>

// Problem: B=4, N=4096, D_MODEL=1024, H=16, DEPTH=64 (linear attention + LN)
// Pipeline: wtrans -> [conv->gemm]x3 (QKV; elu+1 on Q/K; fused q_sum on Q; fused Z on K)
//           -> ktq_partial -> ktq_reduce -> stagec -> gemm(Wo) -> LN
// R1: fused q_sum into QKV GEMM epilogue (was 380us standalone).
// R2: fp32->bf16 conv pass + pure-bf16 GEMM (global_load_lds both operands) + XCD swizzle.
// R3: ktq split into 8 n-slabs (512 blocks, fp32 partials + reduce) — was 85us at 2.6%
//     occupancy with 64 blocks. Z=K.q_sum fused into K-GEMM epilogue (wave holds a full
//     head's 64 cols; shfl_xor reduce) — stagec drops its 33MB strided K re-read.

typedef __attribute__((ext_vector_type(8))) short short8;
typedef __attribute__((ext_vector_type(4))) float floatx4;
typedef __attribute__((ext_vector_type(4))) unsigned short ushortx4;
typedef __attribute__((ext_vector_type(8))) unsigned short ushortx8;

#define DEVINL __device__ __forceinline__

DEVINL unsigned short f2bf(float f) {
  unsigned int u = __builtin_bit_cast(unsigned int, f);
  u += 0x7fffu + ((u >> 16) & 1u);            // RNE
  return (unsigned short)(u >> 16);
}
DEVINL float bf2f(unsigned short h) {
  unsigned int u = ((unsigned int)h) << 16;
  return __builtin_bit_cast(float, u);
}
// async global->LDS, 16B per lane; LDS dest = wave-uniform base + lane*16
DEVINL void g2l16(const void* g, void* l) {
  __builtin_amdgcn_global_load_lds((const __attribute__((address_space(1))) void*)g,
                                   (__attribute__((address_space(3))) void*)l, 16, 0, 0);
}

// ---------------- fp32 -> bf16 elementwise (memory-bound) ----------------
__global__ __launch_bounds__(256) void conv_kernel(const float* __restrict__ in,
                                                   unsigned short* __restrict__ out) {
  const size_t i = ((size_t)blockIdx.x * 256 + threadIdx.x) * 8;
  const float4 a = *(const float4*)(in + i);
  const float4 b = *(const float4*)(in + i + 4);
  ushortx8 o;
  o[0] = f2bf(a.x); o[1] = f2bf(a.y); o[2] = f2bf(a.z); o[3] = f2bf(a.w);
  o[4] = f2bf(b.x); o[5] = f2bf(b.y); o[6] = f2bf(b.z); o[7] = f2bf(b.w);
  *(ushortx8*)(out + i) = o;
}

// ---------------- weight transpose + fp32->bf16 ----------------
struct W4 { const float* w[4]; };

__global__ __launch_bounds__(256) void wtrans_kernel(W4 wp, unsigned short* wt) {
  const int z = blockIdx.z;
  const float* W = wp.w[z];
  unsigned short* WT = wt + (size_t)z * 1024 * 1024;
  __shared__ float tile[32][33];
  const int bx = blockIdx.x, by = blockIdx.y;
  const int t = threadIdx.x, r = t >> 5, c = t & 31;
#pragma unroll
  for (int p = 0; p < 4; ++p)
    tile[p * 8 + r][c] = W[(size_t)(by * 32 + p * 8 + r) * 1024 + bx * 32 + c];
  __syncthreads();
#pragma unroll
  for (int p = 0; p < 4; ++p)
    WT[(size_t)(bx * 32 + p * 8 + r) * 1024 + by * 32 + c] = f2bf(tile[c][p * 8 + r]);
}

// ---------------- main GEMM: C[M,N] = A[M,K] * BT[N,K]^T + bias ----------------
// opt: elu+1 (act), fused column-sum q_sum (qsflag), fused Z=C.qsum per head (zflag).
// grid = (M/128)*(N/128) 1D, m-fastest id => the 8 n-blocks sharing an A panel map to
// the same XCD (id%8 == m_idx%8 since M/128 % 8 == 0).
__global__ __launch_bounds__(256) void gemm_bt_kernel(const unsigned short* __restrict__ A,
                                                      const unsigned short* __restrict__ BT,
                                                      const float* __restrict__ bias,
                                                      unsigned short* __restrict__ C,
                                                      int act, int qsflag, int zflag,
                                                      float* qsum, float* Z,
                                                      int M, int N, int K) {
  const int mb = M >> 7;
  const int id = blockIdx.x;
  const int m0 = (id % mb) * 128;
  const int n0 = (id / mb) * 128;
  __shared__ unsigned short lA[128 * 32];
  __shared__ unsigned short lB[128 * 32];
  const int t = threadIdx.x, lane = t & 63, wave = t >> 6;
  const int wm = wave >> 1, wn = wave & 1;

  floatx4 acc[4][4] = {};

  const int srow = lane >> 2;        // row-in-chunk for g2l staging
  const int scol = (lane & 3) * 8;   // elem col

  for (int k0 = 0; k0 < K; k0 += 32) {
    __syncthreads();
    // stage A and B tiles (bf16) via global_load_lds: 8 chunks of 16 rows each, 2/wave
#pragma unroll
    for (int i = 0; i < 2; ++i) {
      const int c = wave * 2 + i;
      g2l16(BT + (size_t)(n0 + c * 16 + srow) * K + (k0 + scol), (void*)&lB[c * 512]);
      g2l16(A + (size_t)(m0 + c * 16 + srow) * K + (k0 + scol), (void*)&lA[c * 512]);
    }
    __syncthreads();
    short8 af[4], bfr[4];
#pragma unroll
    for (int mt = 0; mt < 4; ++mt)
      af[mt] = *(const short8*)&lA[(wm * 64 + mt * 16 + (lane & 15)) * 32 + (lane >> 4) * 8];
#pragma unroll
    for (int nt = 0; nt < 4; ++nt)
      bfr[nt] = *(const short8*)&lB[(wn * 64 + nt * 16 + (lane & 15)) * 32 + (lane >> 4) * 8];
#pragma unroll
    for (int mt = 0; mt < 4; ++mt)
#pragma unroll
      for (int nt = 0; nt < 4; ++nt)
        acc[mt][nt] = __builtin_amdgcn_mfma_f32_16x16x32_bf16(af[mt], bfr[nt], acc[mt][nt], 0, 0, 0);
  }

  // epilogue: C/D layout col=lane&15, row=(lane>>4)*4+reg
  const int bb = m0 >> 12;   // 128-row tiles never straddle a batch (4096 % 128 == 0)
  float cs[4] = {0.f, 0.f, 0.f, 0.f};   // per-lane column partial sums (16 rows each)
  float zp[4][4] = {};                   // per-lane Z partials [mt][r]
#pragma unroll
  for (int nt = 0; nt < 4; ++nt) {
    const int colg = n0 + wn * 64 + nt * 16 + (lane & 15);
    const float bv = bias[colg];
    float qsv = 0.f;
    if (zflag) qsv = qsum[(bb * 16 + (colg >> 6)) * 64 + (colg & 63)];
#pragma unroll
    for (int mt = 0; mt < 4; ++mt) {
#pragma unroll
      for (int r = 0; r < 4; ++r) {
        const int rowg = m0 + wm * 64 + mt * 16 + (lane >> 4) * 4 + r;
        float v = acc[mt][nt][r] + bv;
        if (act) v = (v > 0.f) ? (v + 1.f) : __expf(v);   // elu(x)+1
        cs[nt] += v;
        if (zflag) zp[mt][r] += v * qsv;
        C[(size_t)rowg * N + colg] = f2bf(v);
      }
    }
  }
  if (qsflag) {
#pragma unroll
    for (int nt = 0; nt < 4; ++nt) {
      float v = cs[nt];
      v += __shfl_xor(v, 16);
      v += __shfl_xor(v, 32);   // lanes 0..15 hold the full 64-row column sum of this wave
      if (lane < 16) {
        const int colg = n0 + wn * 64 + nt * 16 + lane;
        atomicAdd(&qsum[(bb * 16 + (colg >> 6)) * 64 + (colg & 63)], v);
      }
    }
  }
  if (zflag) {
    // wave wn covers ALL 64 cols of head h: reduce over lane&15 -> full Z per row
    const int h = (n0 >> 6) + wn;
#pragma unroll
    for (int mt = 0; mt < 4; ++mt) {
#pragma unroll
      for (int r = 0; r < 4; ++r) {
        float v = zp[mt][r];
        v += __shfl_xor(v, 1); v += __shfl_xor(v, 2);
        v += __shfl_xor(v, 4); v += __shfl_xor(v, 8);
        if ((lane & 15) == 0) {
          const int rowg = m0 + wm * 64 + mt * 16 + (lane >> 4) * 4 + r;
          Z[((size_t)(bb * 16 + h)) * 4096 + (rowg & 4095)] = v;
        }
      }
    }
  }
}

// ---------------- KtQ partials: part[s][bh][e][d] = sum_{n in slab s} K[n,d]*Q[n,e] ----
#define KTS 136  // LDS row stride (ushorts): 272B = 16B-aligned, spreads frag-read banks
__global__ __launch_bounds__(256) void ktq_partial_kernel(const unsigned short* Qp,
                                                          const unsigned short* Kp,
                                                          float* part) {
  const int bh = blockIdx.x, b = bh >> 4, h = bh & 15;
  const int s = blockIdx.y;
  const unsigned short* Qh = Qp + (size_t)b * 4096 * 1024 + h * 64;
  const unsigned short* Kh = Kp + (size_t)b * 4096 * 1024 + h * 64;
  __shared__ unsigned short Kt[64 * KTS];
  __shared__ unsigned short Qt[64 * KTS];
  const int t = threadIdx.x, lane = t & 63, wave = t >> 6;
  floatx4 acc[4] = {};
  const int nlb = t >> 3;            // 0..31
  const int dblk = (t & 7) * 8;

  for (int c0 = s * 512; c0 < s * 512 + 512; c0 += 128) {
    __syncthreads();
#pragma unroll
    for (int it = 0; it < 4; ++it) {
      const int nl = it * 32 + nlb;
      const size_t goff = (size_t)(c0 + nl) * 1024 + dblk;
      short8 kv = *(const short8*)(Kh + goff);
      short8 qv = *(const short8*)(Qh + goff);
#pragma unroll
      for (int j = 0; j < 8; ++j) {
        Kt[(dblk + j) * KTS + nl] = (unsigned short)kv[j];
        Qt[(dblk + j) * KTS + nl] = (unsigned short)qv[j];
      }
    }
    __syncthreads();
#pragma unroll
    for (int ks = 0; ks < 4; ++ks) {
      const short8 a = *(const short8*)&Kt[(wave * 16 + (lane & 15)) * KTS + ks * 32 + (lane >> 4) * 8];
#pragma unroll
      for (int et = 0; et < 4; ++et) {
        const short8 bb = *(const short8*)&Qt[(et * 16 + (lane & 15)) * KTS + ks * 32 + (lane >> 4) * 8];
        acc[et] = __builtin_amdgcn_mfma_f32_16x16x32_bf16(a, bb, acc[et], 0, 0, 0);
      }
    }
  }
  float* outp = part + ((size_t)(s * 64 + bh)) * 4096;
#pragma unroll
  for (int et = 0; et < 4; ++et) {
    const int e = et * 16 + (lane & 15);
#pragma unroll
    for (int r = 0; r < 4; ++r) {
      const int d = wave * 16 + (lane >> 4) * 4 + r;
      outp[e * 64 + d] = acc[et][r];   // transposed store: [e][d]
    }
  }
}

// ---------------- reduce 8 slabs -> bf16 (KtQ)^T[e][d] ----------------
__global__ __launch_bounds__(256) void ktq_reduce_kernel(const float* __restrict__ part,
                                                         unsigned short* __restrict__ ktqt) {
  const int bh = blockIdx.x, t = threadIdx.x;
#pragma unroll
  for (int i = 0; i < 16; ++i) {
    const int idx = i * 256 + t;
    float s = 0.f;
#pragma unroll
    for (int sl = 0; sl < 8; ++sl) s += part[((size_t)(sl * 64 + bh)) * 4096 + idx];
    ktqt[(size_t)bh * 4096 + idx] = f2bf(s);
  }
}

// ---------------- U[b,n,h*64+e] = (sum_d V[n,d]*KtQ[d,e]) / (Z[b,h,n] + eps) ----------------
#define CTS 72  // kt_lds row stride: 144B = 16B-aligned, bank-spread
__global__ __launch_bounds__(256) void stagec_kernel(const unsigned short* Vp,
                                                     const unsigned short* ktqt,
                                                     const float* __restrict__ Z,
                                                     unsigned short* U) {
  const int bh = blockIdx.y, b = bh >> 4, h = bh & 15;
  const int n0 = blockIdx.x * 256;
  __shared__ unsigned short kt_lds[64 * CTS];
  __shared__ float zbuf[256];
  const int t = threadIdx.x, lane = t & 63, wave = t >> 6;

  {
    const unsigned short* src = ktqt + (size_t)bh * 4096;
    const int row = t >> 2, seg = (t & 3) * 16;
    *(short8*)&kt_lds[row * CTS + seg] = *(const short8*)(src + row * 64 + seg);
    *(short8*)&kt_lds[row * CTS + seg + 8] = *(const short8*)(src + row * 64 + seg + 8);
  }
  zbuf[t] = Z[(size_t)bh * 4096 + n0 + t];
  __syncthreads();

  const unsigned short* Vh = Vp + (size_t)b * 4096 * 1024 + h * 64;
  floatx4 acc[4][4] = {};
#pragma unroll
  for (int ks = 0; ks < 2; ++ks) {
    short8 bfr[4];
#pragma unroll
    for (int et = 0; et < 4; ++et)
      bfr[et] = *(const short8*)&kt_lds[(et * 16 + (lane & 15)) * CTS + ks * 32 + (lane >> 4) * 8];
#pragma unroll
    for (int mt = 0; mt < 4; ++mt) {
      const short8 a = *(const short8*)(Vh + (size_t)(n0 + wave * 64 + mt * 16 + (lane & 15)) * 1024 +
                                        ks * 32 + (lane >> 4) * 8);
#pragma unroll
      for (int et = 0; et < 4; ++et)
        acc[mt][et] = __builtin_amdgcn_mfma_f32_16x16x32_bf16(a, bfr[et], acc[mt][et], 0, 0, 0);
    }
  }
#pragma unroll
  for (int mt = 0; mt < 4; ++mt) {
#pragma unroll
    for (int r = 0; r < 4; ++r) {
      const int rl = wave * 64 + mt * 16 + (lane >> 4) * 4 + r;
      const float inv = 1.0f / (zbuf[rl] + 1e-9f);
#pragma unroll
      for (int et = 0; et < 4; ++et) {
        const int e = et * 16 + (lane & 15);
        U[((size_t)b * 4096 + n0 + rl) * 1024 + h * 64 + e] = f2bf(acc[mt][et][r] * inv);
      }
    }
  }
}

// ---------------- residual + LayerNorm ----------------
__global__ __launch_bounds__(256) void ln_kernel(const float* query, const unsigned short* attn,
                                                 const float* gamma, const float* beta, float* out) {
  const int row = blockIdx.x, t = threadIdx.x;
  const float* qrow = query + (size_t)row * 1024;
  const unsigned short* arow = attn + (size_t)row * 1024;
  const float4 qv = *(const float4*)(qrow + t * 4);
  const ushortx4 av = *(const ushortx4*)(arow + t * 4);
  float x0 = qv.x + bf2f(av.x), x1 = qv.y + bf2f(av.y);
  float x2 = qv.z + bf2f(av.z), x3 = qv.w + bf2f(av.w);
  float s = x0 + x1 + x2 + x3;
  float s2 = x0 * x0 + x1 * x1 + x2 * x2 + x3 * x3;
  for (int off = 32; off > 0; off >>= 1) {
    s += __shfl_down(s, off);
    s2 += __shfl_down(s2, off);
  }
  __shared__ float lred[8];
  if ((t & 63) == 0) { lred[(t >> 6) * 2] = s; lred[(t >> 6) * 2 + 1] = s2; }
  __syncthreads();
  s = lred[0] + lred[2] + lred[4] + lred[6];
  s2 = lred[1] + lred[3] + lred[5] + lred[7];
  const float mu = s * (1.f / 1024.f);
  const float var = s2 * (1.f / 1024.f) - mu * mu;
  const float rstd = rsqrtf(var + 1e-6f);
  float4 o;
  o.x = (x0 - mu) * rstd * gamma[t * 4 + 0] + beta[t * 4 + 0];
  o.y = (x1 - mu) * rstd * gamma[t * 4 + 1] + beta[t * 4 + 1];
  o.z = (x2 - mu) * rstd * gamma[t * 4 + 2] + beta[t * 4 + 2];
  o.w = (x3 - mu) * rstd * gamma[t * 4 + 3] + beta[t * 4 + 3];
  *(float4*)(out + (size_t)row * 1024 + t * 4) = o;
}

// ---------------- launch ----------------
extern "C" void kernel_launch(void* const* d_in, const int* in_sizes, int n_in,
                              void* d_out, int out_size, void* d_ws, size_t ws_size,
                              hipStream_t stream) {
  const float* query = (const float*)d_in[0];
  const float* key_  = (const float*)d_in[1];
  const float* value = (const float*)d_in[2];
  const float* Wq = (const float*)d_in[3];
  const float* bq = (const float*)d_in[4];
  const float* Wk = (const float*)d_in[5];
  const float* bk = (const float*)d_in[6];
  const float* Wv = (const float*)d_in[7];
  const float* bv = (const float*)d_in[8];
  const float* Wo = (const float*)d_in[9];
  const float* bo = (const float*)d_in[10];
  const float* gamma = (const float*)d_in[11];
  const float* beta = (const float*)d_in[12];
  float* out = (float*)d_out;

  char* ws = (char*)d_ws;
  // ws layout (~137.6 MiB peak):
  //   abf (32MB, rotating bf16 A; aliased by ktq partials (8MB) then U) | Qp | Kp | Vp
  //   | WT (8MB) | qsum (16KB) | ktqt (512KB) | Z (1MB).  attn aliases Qp.
  unsigned short* abf = (unsigned short*)(ws + 0);
  unsigned short* Qp = (unsigned short*)(ws + 33554432);
  unsigned short* Kp = (unsigned short*)(ws + 67108864);
  unsigned short* Vp = (unsigned short*)(ws + 100663296);
  unsigned short* WT = (unsigned short*)(ws + 134217728);
  float* qsumP = (float*)(ws + 142606336);
  unsigned short* ktqtP = (unsigned short*)(ws + 142606336 + 16384);
  float* Zp = (float*)(ws + 142606336 + 16384 + 524288);
  float* part = (float*)abf;   // 8MB; live only between ktq_partial and ktq_reduce
  unsigned short* U = abf;     // abf dead after gemmV / part dead after reduce
  unsigned short* attn = Qp;   // Qp dead after ktq_partial

  dim3 blk(256);

  W4 w4; w4.w[0] = Wq; w4.w[1] = Wk; w4.w[2] = Wv; w4.w[3] = Wo;
  wtrans_kernel<<<dim3(32, 32, 4), blk, 0, stream>>>(w4, WT);

  // zero the fused q_sum accumulator (16 KB)
  hipMemsetAsync(qsumP, 0, 64 * 64 * sizeof(float), stream);

  const int convGrid = 8192;      // 16384*1024 / (256*8)
  const int gemmGrid = 128 * 8;   // (M/128)*(N/128)

  conv_kernel<<<convGrid, blk, 0, stream>>>(query, abf);
  gemm_bt_kernel<<<gemmGrid, blk, 0, stream>>>(abf, WT, bq, Qp, 1, 1, 0, qsumP, Zp,
                                               16384, 1024, 1024);

  conv_kernel<<<convGrid, blk, 0, stream>>>(key_, abf);
  gemm_bt_kernel<<<gemmGrid, blk, 0, stream>>>(abf, WT + 1024 * 1024, bk, Kp, 1, 0, 1,
                                               qsumP, Zp, 16384, 1024, 1024);

  conv_kernel<<<convGrid, blk, 0, stream>>>(value, abf);
  gemm_bt_kernel<<<gemmGrid, blk, 0, stream>>>(abf, WT + 2 * 1024 * 1024, bv, Vp, 0, 0, 0,
                                               qsumP, Zp, 16384, 1024, 1024);

  ktq_partial_kernel<<<dim3(64, 8), blk, 0, stream>>>(Qp, Kp, part);
  ktq_reduce_kernel<<<64, blk, 0, stream>>>(part, ktqtP);
  stagec_kernel<<<dim3(16, 64), blk, 0, stream>>>(Vp, ktqtP, Zp, U);

  gemm_bt_kernel<<<gemmGrid, blk, 0, stream>>>(U, WT + 3 * 1024 * 1024, bo, attn, 0, 0, 0,
                                               qsumP, Zp, 16384, 1024, 1024);

  ln_kernel<<<16384, blk, 0, stream>>>(query, attn, gamma, beta, out);
}

// Round 5
// 576.074 us; speedup vs baseline: 1.7356x; 1.0660x over previous
//
#include <hip/hip_runtime.h>
#include <hip/hip_bf16.h>

// Problem: B=4, N=4096, D_MODEL=1024, H=16, DEPTH=64 (linear attention + LN)
// Pipeline: wtrans -> [conv->gemm]x3 (QKV; elu+1 on Q/K; fused q_sum on Q; fused Z on K)
//           -> ktq_partial -> ktq_reduce -> stagec -> gemm(Wo) -> LN
// R1: fused q_sum into QKV GEMM epilogue. R2: conv pass + pure-bf16 GEMM + XCD swizzle.
// R3: ktq 8-way n-slab split; Z fused into K-GEMM epilogue.
// R4: GEMM was LDS-conflict-bound (4.2M conflicts, 8-way on frag reads) + 2.4x write
//     amplification (81MB vs 33.5MB, scalar 2B stores). XOR-swizzle LDS (chunk ^= (row>>1)&3,
//     via lane->global permute on the g2l16 side) -> 2-way (free). Epilogue: bf16 C-tile
//     staged in LDS (128x136), stored as 256B-contiguous dwordx4 rows.

typedef __attribute__((ext_vector_type(8))) short short8;
typedef __attribute__((ext_vector_type(4))) float floatx4;
typedef __attribute__((ext_vector_type(4))) unsigned short ushortx4;
typedef __attribute__((ext_vector_type(8))) unsigned short ushortx8;

#define DEVINL __device__ __forceinline__

DEVINL unsigned short f2bf(float f) {
  unsigned int u = __builtin_bit_cast(unsigned int, f);
  u += 0x7fffu + ((u >> 16) & 1u);            // RNE
  return (unsigned short)(u >> 16);
}
DEVINL float bf2f(unsigned short h) {
  unsigned int u = ((unsigned int)h) << 16;
  return __builtin_bit_cast(float, u);
}
// async global->LDS, 16B per lane; LDS dest = wave-uniform base + lane*16
DEVINL void g2l16(const void* g, void* l) {
  __builtin_amdgcn_global_load_lds((const __attribute__((address_space(1))) void*)g,
                                   (__attribute__((address_space(3))) void*)l, 16, 0, 0);
}

// ---------------- fp32 -> bf16 elementwise (memory-bound) ----------------
__global__ __launch_bounds__(256) void conv_kernel(const float* __restrict__ in,
                                                   unsigned short* __restrict__ out) {
  const size_t i = ((size_t)blockIdx.x * 256 + threadIdx.x) * 8;
  const float4 a = *(const float4*)(in + i);
  const float4 b = *(const float4*)(in + i + 4);
  ushortx8 o;
  o[0] = f2bf(a.x); o[1] = f2bf(a.y); o[2] = f2bf(a.z); o[3] = f2bf(a.w);
  o[4] = f2bf(b.x); o[5] = f2bf(b.y); o[6] = f2bf(b.z); o[7] = f2bf(b.w);
  *(ushortx8*)(out + i) = o;
}

// ---------------- weight transpose + fp32->bf16 ----------------
struct W4 { const float* w[4]; };

__global__ __launch_bounds__(256) void wtrans_kernel(W4 wp, unsigned short* wt) {
  const int z = blockIdx.z;
  const float* W = wp.w[z];
  unsigned short* WT = wt + (size_t)z * 1024 * 1024;
  __shared__ float tile[32][33];
  const int bx = blockIdx.x, by = blockIdx.y;
  const int t = threadIdx.x, r = t >> 5, c = t & 31;
#pragma unroll
  for (int p = 0; p < 4; ++p)
    tile[p * 8 + r][c] = W[(size_t)(by * 32 + p * 8 + r) * 1024 + bx * 32 + c];
  __syncthreads();
#pragma unroll
  for (int p = 0; p < 4; ++p)
    WT[(size_t)(bx * 32 + p * 8 + r) * 1024 + by * 32 + c] = f2bf(tile[c][p * 8 + r]);
}

// ---------------- main GEMM: C[M,N] = A[M,K] * BT[N,K]^T + bias ----------------
// opt: elu+1 (act), fused column-sum q_sum (qsflag), fused Z=C.qsum per head (zflag).
// grid = (M/128)*(N/128) 1D, m-fastest id => 8 n-blocks sharing an A panel on one XCD.
// LDS swizzle: global k-chunk q of row r stored at chunk position q ^ ((r>>1)&3).
#define CT_S 136   // epilogue C-tile row stride (ushorts); 272B = 16B-aligned
__global__ __launch_bounds__(256) void gemm_bt_kernel(const unsigned short* __restrict__ A,
                                                      const unsigned short* __restrict__ BT,
                                                      const float* __restrict__ bias,
                                                      unsigned short* __restrict__ C,
                                                      int act, int qsflag, int zflag,
                                                      float* qsum, float* Z,
                                                      int M, int N, int K) {
  const int mb = M >> 7;
  const int id = blockIdx.x;
  const int m0 = (id % mb) * 128;
  const int n0 = (id / mb) * 128;
  __shared__ unsigned short smem[128 * CT_S];   // k-loop: lA(4096)+lB(4096); epilogue: C-tile
  unsigned short* lA = smem;
  unsigned short* lB = smem + 4096;
  const int t = threadIdx.x, lane = t & 63, wave = t >> 6;
  const int wm = wave >> 1, wn = wave & 1;

  floatx4 acc[4][4] = {};

  const int srow = lane >> 2;                       // row-in-chunk for g2l staging
  const int scol = ((lane & 3) ^ ((srow >> 1) & 3)) * 8;  // swizzled global k-chunk
  // frag-read swizzle (uniform over mt/nt: row bits 1..2 come from lane&15)
  const int rl = lane & 15;
  const int rchunk = ((lane >> 4) ^ ((rl >> 1) & 3)) * 8;

  for (int k0 = 0; k0 < K; k0 += 32) {
    __syncthreads();
#pragma unroll
    for (int i = 0; i < 2; ++i) {
      const int c = wave * 2 + i;
      g2l16(BT + (size_t)(n0 + c * 16 + srow) * K + (k0 + scol), (void*)&lB[c * 512]);
      g2l16(A + (size_t)(m0 + c * 16 + srow) * K + (k0 + scol), (void*)&lA[c * 512]);
    }
    __syncthreads();
    short8 af[4], bfr[4];
#pragma unroll
    for (int mt = 0; mt < 4; ++mt)
      af[mt] = *(const short8*)&lA[(wm * 64 + mt * 16 + rl) * 32 + rchunk];
#pragma unroll
    for (int nt = 0; nt < 4; ++nt)
      bfr[nt] = *(const short8*)&lB[(wn * 64 + nt * 16 + rl) * 32 + rchunk];
#pragma unroll
    for (int mt = 0; mt < 4; ++mt)
#pragma unroll
      for (int nt = 0; nt < 4; ++nt)
        acc[mt][nt] = __builtin_amdgcn_mfma_f32_16x16x32_bf16(af[mt], bfr[nt], acc[mt][nt], 0, 0, 0);
  }

  // ---- epilogue: C/D layout col=lane&15, row=(lane>>4)*4+reg ----
  const int bb = m0 >> 12;   // 128-row tiles never straddle a batch
  float cs[4] = {0.f, 0.f, 0.f, 0.f};   // per-lane column partials (16 rows each)
  float zp[4][4] = {};                   // per-lane Z partials [mt][r]
  __syncthreads();                       // all waves done with lA/lB before C-tile reuse
#pragma unroll
  for (int nt = 0; nt < 4; ++nt) {
    const int coll = wn * 64 + nt * 16 + (lane & 15);
    const int colg = n0 + coll;
    const float bv = bias[colg];
    float qsv = 0.f;
    if (zflag) qsv = qsum[(bb * 16 + (colg >> 6)) * 64 + (colg & 63)];
#pragma unroll
    for (int mt = 0; mt < 4; ++mt) {
#pragma unroll
      for (int r = 0; r < 4; ++r) {
        const int rowl = wm * 64 + mt * 16 + (lane >> 4) * 4 + r;
        float v = acc[mt][nt][r] + bv;
        if (act) v = (v > 0.f) ? (v + 1.f) : __expf(v);   // elu(x)+1
        cs[nt] += v;
        if (zflag) zp[mt][r] += v * qsv;
        smem[rowl * CT_S + coll] = f2bf(v);
      }
    }
  }
  if (qsflag) {
#pragma unroll
    for (int nt = 0; nt < 4; ++nt) {
      float v = cs[nt];
      v += __shfl_xor(v, 16);
      v += __shfl_xor(v, 32);   // lanes 0..15 hold the full 64-row column sum
      if (lane < 16) {
        const int colg = n0 + wn * 64 + nt * 16 + lane;
        atomicAdd(&qsum[(bb * 16 + (colg >> 6)) * 64 + (colg & 63)], v);
      }
    }
  }
  if (zflag) {
    // wave wn covers ALL 64 cols of head h: reduce over lane&15 -> full Z per row
    const int h = (n0 >> 6) + wn;
#pragma unroll
    for (int mt = 0; mt < 4; ++mt) {
#pragma unroll
      for (int r = 0; r < 4; ++r) {
        float v = zp[mt][r];
        v += __shfl_xor(v, 1); v += __shfl_xor(v, 2);
        v += __shfl_xor(v, 4); v += __shfl_xor(v, 8);
        if ((lane & 15) == 0) {
          const int rowg = m0 + wm * 64 + mt * 16 + (lane >> 4) * 4 + r;
          Z[((size_t)(bb * 16 + h)) * 4096 + (rowg & 4095)] = v;
        }
      }
    }
  }
  __syncthreads();
  // coalesced C store: 16 threads x 16B = 256B contiguous per row, 16 rows/pass
  {
    const int cc = (t & 15) * 8;
#pragma unroll
    for (int p = 0; p < 8; ++p) {
      const int row = p * 16 + (t >> 4);
      *(short8*)(C + (size_t)(m0 + row) * N + n0 + cc) = *(const short8*)&smem[row * CT_S + cc];
    }
  }
}

// ---------------- KtQ partials: part[s][bh][e][d] = sum_{n in slab s} K[n,d]*Q[n,e] ----
#define KTS 136  // LDS row stride (ushorts): 272B = 16B-aligned, spreads frag-read banks
__global__ __launch_bounds__(256) void ktq_partial_kernel(const unsigned short* Qp,
                                                          const unsigned short* Kp,
                                                          float* part) {
  const int bh = blockIdx.x, b = bh >> 4, h = bh & 15;
  const int s = blockIdx.y;
  const unsigned short* Qh = Qp + (size_t)b * 4096 * 1024 + h * 64;
  const unsigned short* Kh = Kp + (size_t)b * 4096 * 1024 + h * 64;
  __shared__ unsigned short Kt[64 * KTS];
  __shared__ unsigned short Qt[64 * KTS];
  const int t = threadIdx.x, lane = t & 63, wave = t >> 6;
  floatx4 acc[4] = {};
  const int nlb = t >> 3;            // 0..31
  const int dblk = (t & 7) * 8;

  for (int c0 = s * 512; c0 < s * 512 + 512; c0 += 128) {
    __syncthreads();
#pragma unroll
    for (int it = 0; it < 4; ++it) {
      const int nl = it * 32 + nlb;
      const size_t goff = (size_t)(c0 + nl) * 1024 + dblk;
      short8 kv = *(const short8*)(Kh + goff);
      short8 qv = *(const short8*)(Qh + goff);
#pragma unroll
      for (int j = 0; j < 8; ++j) {
        Kt[(dblk + j) * KTS + nl] = (unsigned short)kv[j];
        Qt[(dblk + j) * KTS + nl] = (unsigned short)qv[j];
      }
    }
    __syncthreads();
#pragma unroll
    for (int ks = 0; ks < 4; ++ks) {
      const short8 a = *(const short8*)&Kt[(wave * 16 + (lane & 15)) * KTS + ks * 32 + (lane >> 4) * 8];
#pragma unroll
      for (int et = 0; et < 4; ++et) {
        const short8 bb = *(const short8*)&Qt[(et * 16 + (lane & 15)) * KTS + ks * 32 + (lane >> 4) * 8];
        acc[et] = __builtin_amdgcn_mfma_f32_16x16x32_bf16(a, bb, acc[et], 0, 0, 0);
      }
    }
  }
  float* outp = part + ((size_t)(s * 64 + bh)) * 4096;
#pragma unroll
  for (int et = 0; et < 4; ++et) {
    const int e = et * 16 + (lane & 15);
#pragma unroll
    for (int r = 0; r < 4; ++r) {
      const int d = wave * 16 + (lane >> 4) * 4 + r;
      outp[e * 64 + d] = acc[et][r];   // transposed store: [e][d]
    }
  }
}

// ---------------- reduce 8 slabs -> bf16 (KtQ)^T[e][d] ----------------
__global__ __launch_bounds__(256) void ktq_reduce_kernel(const float* __restrict__ part,
                                                         unsigned short* __restrict__ ktqt) {
  const int bh = blockIdx.x, t = threadIdx.x;
#pragma unroll
  for (int i = 0; i < 16; ++i) {
    const int idx = i * 256 + t;
    float s = 0.f;
#pragma unroll
    for (int sl = 0; sl < 8; ++sl) s += part[((size_t)(sl * 64 + bh)) * 4096 + idx];
    ktqt[(size_t)bh * 4096 + idx] = f2bf(s);
  }
}

// ---------------- U[b,n,h*64+e] = (sum_d V[n,d]*KtQ[d,e]) / (Z[b,h,n] + eps) ----------------
#define CTS 72  // kt_lds row stride: 144B = 16B-aligned, bank-spread
__global__ __launch_bounds__(256) void stagec_kernel(const unsigned short* Vp,
                                                     const unsigned short* ktqt,
                                                     const float* __restrict__ Z,
                                                     unsigned short* U) {
  const int bh = blockIdx.y, b = bh >> 4, h = bh & 15;
  const int n0 = blockIdx.x * 256;
  __shared__ unsigned short kt_lds[64 * CTS];
  __shared__ float zbuf[256];
  const int t = threadIdx.x, lane = t & 63, wave = t >> 6;

  {
    const unsigned short* src = ktqt + (size_t)bh * 4096;
    const int row = t >> 2, seg = (t & 3) * 16;
    *(short8*)&kt_lds[row * CTS + seg] = *(const short8*)(src + row * 64 + seg);
    *(short8*)&kt_lds[row * CTS + seg + 8] = *(const short8*)(src + row * 64 + seg + 8);
  }
  zbuf[t] = Z[(size_t)bh * 4096 + n0 + t];
  __syncthreads();

  const unsigned short* Vh = Vp + (size_t)b * 4096 * 1024 + h * 64;
  floatx4 acc[4][4] = {};
#pragma unroll
  for (int ks = 0; ks < 2; ++ks) {
    short8 bfr[4];
#pragma unroll
    for (int et = 0; et < 4; ++et)
      bfr[et] = *(const short8*)&kt_lds[(et * 16 + (lane & 15)) * CTS + ks * 32 + (lane >> 4) * 8];
#pragma unroll
    for (int mt = 0; mt < 4; ++mt) {
      const short8 a = *(const short8*)(Vh + (size_t)(n0 + wave * 64 + mt * 16 + (lane & 15)) * 1024 +
                                        ks * 32 + (lane >> 4) * 8);
#pragma unroll
      for (int et = 0; et < 4; ++et)
        acc[mt][et] = __builtin_amdgcn_mfma_f32_16x16x32_bf16(a, bfr[et], acc[mt][et], 0, 0, 0);
    }
  }
#pragma unroll
  for (int mt = 0; mt < 4; ++mt) {
#pragma unroll
    for (int r = 0; r < 4; ++r) {
      const int rl = wave * 64 + mt * 16 + (lane >> 4) * 4 + r;
      const float inv = 1.0f / (zbuf[rl] + 1e-9f);
#pragma unroll
      for (int et = 0; et < 4; ++et) {
        const int e = et * 16 + (lane & 15);
        U[((size_t)b * 4096 + n0 + rl) * 1024 + h * 64 + e] = f2bf(acc[mt][et][r] * inv);
      }
    }
  }
}

// ---------------- residual + LayerNorm ----------------
__global__ __launch_bounds__(256) void ln_kernel(const float* query, const unsigned short* attn,
                                                 const float* gamma, const float* beta, float* out) {
  const int row = blockIdx.x, t = threadIdx.x;
  const float* qrow = query + (size_t)row * 1024;
  const unsigned short* arow = attn + (size_t)row * 1024;
  const float4 qv = *(const float4*)(qrow + t * 4);
  const ushortx4 av = *(const ushortx4*)(arow + t * 4);
  float x0 = qv.x + bf2f(av.x), x1 = qv.y + bf2f(av.y);
  float x2 = qv.z + bf2f(av.z), x3 = qv.w + bf2f(av.w);
  float s = x0 + x1 + x2 + x3;
  float s2 = x0 * x0 + x1 * x1 + x2 * x2 + x3 * x3;
  for (int off = 32; off > 0; off >>= 1) {
    s += __shfl_down(s, off);
    s2 += __shfl_down(s2, off);
  }
  __shared__ float lred[8];
  if ((t & 63) == 0) { lred[(t >> 6) * 2] = s; lred[(t >> 6) * 2 + 1] = s2; }
  __syncthreads();
  s = lred[0] + lred[2] + lred[4] + lred[6];
  s2 = lred[1] + lred[3] + lred[5] + lred[7];
  const float mu = s * (1.f / 1024.f);
  const float var = s2 * (1.f / 1024.f) - mu * mu;
  const float rstd = rsqrtf(var + 1e-6f);
  float4 o;
  o.x = (x0 - mu) * rstd * gamma[t * 4 + 0] + beta[t * 4 + 0];
  o.y = (x1 - mu) * rstd * gamma[t * 4 + 1] + beta[t * 4 + 1];
  o.z = (x2 - mu) * rstd * gamma[t * 4 + 2] + beta[t * 4 + 2];
  o.w = (x3 - mu) * rstd * gamma[t * 4 + 3] + beta[t * 4 + 3];
  *(float4*)(out + (size_t)row * 1024 + t * 4) = o;
}

// ---------------- launch ----------------
extern "C" void kernel_launch(void* const* d_in, const int* in_sizes, int n_in,
                              void* d_out, int out_size, void* d_ws, size_t ws_size,
                              hipStream_t stream) {
  const float* query = (const float*)d_in[0];
  const float* key_  = (const float*)d_in[1];
  const float* value = (const float*)d_in[2];
  const float* Wq = (const float*)d_in[3];
  const float* bq = (const float*)d_in[4];
  const float* Wk = (const float*)d_in[5];
  const float* bk = (const float*)d_in[6];
  const float* Wv = (const float*)d_in[7];
  const float* bv = (const float*)d_in[8];
  const float* Wo = (const float*)d_in[9];
  const float* bo = (const float*)d_in[10];
  const float* gamma = (const float*)d_in[11];
  const float* beta = (const float*)d_in[12];
  float* out = (float*)d_out;

  char* ws = (char*)d_ws;
  // ws layout (~137.6 MiB peak):
  //   abf (32MB, rotating bf16 A; aliased by ktq partials (8MB) then U) | Qp | Kp | Vp
  //   | WT (8MB) | qsum (16KB) | ktqt (512KB) | Z (1MB).  attn aliases Qp.
  unsigned short* abf = (unsigned short*)(ws + 0);
  unsigned short* Qp = (unsigned short*)(ws + 33554432);
  unsigned short* Kp = (unsigned short*)(ws + 67108864);
  unsigned short* Vp = (unsigned short*)(ws + 100663296);
  unsigned short* WT = (unsigned short*)(ws + 134217728);
  float* qsumP = (float*)(ws + 142606336);
  unsigned short* ktqtP = (unsigned short*)(ws + 142606336 + 16384);
  float* Zp = (float*)(ws + 142606336 + 16384 + 524288);
  float* part = (float*)abf;   // 8MB; live only between ktq_partial and ktq_reduce
  unsigned short* U = abf;     // abf dead after gemmV / part dead after reduce
  unsigned short* attn = Qp;   // Qp dead after ktq_partial

  dim3 blk(256);

  W4 w4; w4.w[0] = Wq; w4.w[1] = Wk; w4.w[2] = Wv; w4.w[3] = Wo;
  wtrans_kernel<<<dim3(32, 32, 4), blk, 0, stream>>>(w4, WT);

  // zero the fused q_sum accumulator (16 KB)
  hipMemsetAsync(qsumP, 0, 64 * 64 * sizeof(float), stream);

  const int convGrid = 8192;      // 16384*1024 / (256*8)
  const int gemmGrid = 128 * 8;   // (M/128)*(N/128)

  conv_kernel<<<convGrid, blk, 0, stream>>>(query, abf);
  gemm_bt_kernel<<<gemmGrid, blk, 0, stream>>>(abf, WT, bq, Qp, 1, 1, 0, qsumP, Zp,
                                               16384, 1024, 1024);

  conv_kernel<<<convGrid, blk, 0, stream>>>(key_, abf);
  gemm_bt_kernel<<<gemmGrid, blk, 0, stream>>>(abf, WT + 1024 * 1024, bk, Kp, 1, 0, 1,
                                               qsumP, Zp, 16384, 1024, 1024);

  conv_kernel<<<convGrid, blk, 0, stream>>>(value, abf);
  gemm_bt_kernel<<<gemmGrid, blk, 0, stream>>>(abf, WT + 2 * 1024 * 1024, bv, Vp, 0, 0, 0,
                                               qsumP, Zp, 16384, 1024, 1024);

  ktq_partial_kernel<<<dim3(64, 8), blk, 0, stream>>>(Qp, Kp, part);
  ktq_reduce_kernel<<<64, blk, 0, stream>>>(part, ktqtP);
  stagec_kernel<<<dim3(16, 64), blk, 0, stream>>>(Vp, ktqtP, Zp, U);

  gemm_bt_kernel<<<gemmGrid, blk, 0, stream>>>(U, WT + 3 * 1024 * 1024, bo, attn, 0, 0, 0,
                                               qsumP, Zp, 16384, 1024, 1024);

  ln_kernel<<<16384, blk, 0, stream>>>(query, attn, gamma, beta, out);
}

// Round 6
// 565.886 us; speedup vs baseline: 1.7669x; 1.0180x over previous
//
#include <hip/hip_runtime.h>
#include <hip/hip_bf16.h>

// Problem: B=4, N=4096, D_MODEL=1024, H=16, DEPTH=64 (linear attention + LN)
// Pipeline: wtrans -> [conv->gemm]x3 (QKV; elu+1 on Q/K; fused q_sum on Q; fused Z on K)
//           -> ktq_partial -> ktq_reduce -> stagec -> gemm(Wo) -> LN
// R1: fused q_sum into QKV GEMM epilogue. R2: conv pass + pure-bf16 GEMM + XCD swizzle.
// R3: ktq 8-way n-slab split; Z fused into K-GEMM epilogue.
// R4: XOR-swizzled LDS (conflicts 4.2M->131k) + LDS-staged coalesced C store (81->33MB).
// R5: GEMM is barrier/latency-bound (MfmaUtil 18%, VALU 30%, occupancy 22%; LDS floor
//     ~20us vs 72us measured; VGPR=76 -> 128-quantum -> 4 waves/SIMD cap). BK=64 halves
//     the k-iter/barrier count at constant LDS+MFMA work; chunk^ (row&7) swizzle for the
//     128B-row layout; two-pass epilogue (64x136 LDS) keeps LDS at 32KB.

typedef __attribute__((ext_vector_type(8))) short short8;
typedef __attribute__((ext_vector_type(4))) float floatx4;
typedef __attribute__((ext_vector_type(4))) unsigned short ushortx4;
typedef __attribute__((ext_vector_type(8))) unsigned short ushortx8;

#define DEVINL __device__ __forceinline__

DEVINL unsigned short f2bf(float f) {
  unsigned int u = __builtin_bit_cast(unsigned int, f);
  u += 0x7fffu + ((u >> 16) & 1u);            // RNE
  return (unsigned short)(u >> 16);
}
DEVINL float bf2f(unsigned short h) {
  unsigned int u = ((unsigned int)h) << 16;
  return __builtin_bit_cast(float, u);
}
// async global->LDS, 16B per lane; LDS dest = wave-uniform base + lane*16
DEVINL void g2l16(const void* g, void* l) {
  __builtin_amdgcn_global_load_lds((const __attribute__((address_space(1))) void*)g,
                                   (__attribute__((address_space(3))) void*)l, 16, 0, 0);
}

// ---------------- fp32 -> bf16 elementwise (memory-bound) ----------------
__global__ __launch_bounds__(256) void conv_kernel(const float* __restrict__ in,
                                                   unsigned short* __restrict__ out) {
  const size_t i = ((size_t)blockIdx.x * 256 + threadIdx.x) * 8;
  const float4 a = *(const float4*)(in + i);
  const float4 b = *(const float4*)(in + i + 4);
  ushortx8 o;
  o[0] = f2bf(a.x); o[1] = f2bf(a.y); o[2] = f2bf(a.z); o[3] = f2bf(a.w);
  o[4] = f2bf(b.x); o[5] = f2bf(b.y); o[6] = f2bf(b.z); o[7] = f2bf(b.w);
  *(ushortx8*)(out + i) = o;
}

// ---------------- weight transpose + fp32->bf16 ----------------
struct W4 { const float* w[4]; };

__global__ __launch_bounds__(256) void wtrans_kernel(W4 wp, unsigned short* wt) {
  const int z = blockIdx.z;
  const float* W = wp.w[z];
  unsigned short* WT = wt + (size_t)z * 1024 * 1024;
  __shared__ float tile[32][33];
  const int bx = blockIdx.x, by = blockIdx.y;
  const int t = threadIdx.x, r = t >> 5, c = t & 31;
#pragma unroll
  for (int p = 0; p < 4; ++p)
    tile[p * 8 + r][c] = W[(size_t)(by * 32 + p * 8 + r) * 1024 + bx * 32 + c];
  __syncthreads();
#pragma unroll
  for (int p = 0; p < 4; ++p)
    WT[(size_t)(bx * 32 + p * 8 + r) * 1024 + by * 32 + c] = f2bf(tile[c][p * 8 + r]);
}

// ---------------- main GEMM: C[M,N] = A[M,K] * BT[N,K]^T + bias ----------------
// opt: elu+1 (act), fused column-sum q_sum (qsflag), fused Z=C.qsum per head (zflag).
// grid = (M/128)*(N/128) 1D, m-fastest id => 8 n-blocks sharing an A panel on one XCD.
// BK=64; LDS swizzle: col-chunk q (8 elems) of row r stored at position q ^ (r&7).
#define CT_S 136   // epilogue C-tile row stride (ushorts); 272B = 16B-aligned
__global__ __launch_bounds__(256) void gemm_bt_kernel(const unsigned short* __restrict__ A,
                                                      const unsigned short* __restrict__ BT,
                                                      const float* __restrict__ bias,
                                                      unsigned short* __restrict__ C,
                                                      int act, int qsflag, int zflag,
                                                      float* qsum, float* Z,
                                                      int M, int N, int K) {
  const int mb = M >> 7;
  const int id = blockIdx.x;
  const int m0 = (id % mb) * 128;
  const int n0 = (id / mb) * 128;
  __shared__ unsigned short smem[128 * 128];   // k-loop: lA(8192)+lB(8192) ushorts = 32KB
  unsigned short* lA = smem;                   // epilogue: 64 x CT_S reuse (17408 B)
  unsigned short* lB = smem + 8192;
  const int t = threadIdx.x, lane = t & 63, wave = t >> 6;
  const int wm = wave >> 1, wn = wave & 1;

  floatx4 acc[4][4] = {};

  // staging: chunk = 8 rows x 64 cols (1 KB). 16 chunks/operand, 4 per wave.
  const int srow = lane >> 3;                          // 0..7 row-in-chunk
  const int scol = ((lane & 7) ^ srow) * 8;            // swizzled source col-chunk
  // frag reads: row rl (lane&15), logical k-chunk c -> physical c ^ (rl&7)
  const int rl = lane & 15;
  const int qw = lane >> 4;                            // 0..3

  for (int k0 = 0; k0 < K; k0 += 64) {
    __syncthreads();
#pragma unroll
    for (int i = 0; i < 4; ++i) {
      const int c = wave * 4 + i;
      g2l16(BT + (size_t)(n0 + c * 8 + srow) * K + (k0 + scol), (void*)&lB[c * 512]);
      g2l16(A + (size_t)(m0 + c * 8 + srow) * K + (k0 + scol), (void*)&lA[c * 512]);
    }
    __syncthreads();
#pragma unroll
    for (int ks = 0; ks < 2; ++ks) {
      short8 af[4], bfr[4];
#pragma unroll
      for (int mt = 0; mt < 4; ++mt)
        af[mt] = *(const short8*)&lA[(wm * 64 + mt * 16 + rl) * 64 +
                                     (((ks * 4 + qw) ^ (rl & 7)) * 8)];
#pragma unroll
      for (int nt = 0; nt < 4; ++nt)
        bfr[nt] = *(const short8*)&lB[(wn * 64 + nt * 16 + rl) * 64 +
                                      (((ks * 4 + qw) ^ (rl & 7)) * 8)];
#pragma unroll
      for (int mt = 0; mt < 4; ++mt)
#pragma unroll
        for (int nt = 0; nt < 4; ++nt)
          acc[mt][nt] = __builtin_amdgcn_mfma_f32_16x16x32_bf16(af[mt], bfr[nt], acc[mt][nt], 0, 0, 0);
    }
  }

  // ---- epilogue: C/D layout col=lane&15, row=(lane>>4)*4+reg ----
  // two passes of 64 rows through a 64 x CT_S LDS buffer (reuses operand LDS).
  const int bb = m0 >> 12;   // 128-row tiles never straddle a batch
  float cs[4] = {0.f, 0.f, 0.f, 0.f};   // per-lane column partials (16 rows each)
  float zp[4][4] = {};                   // per-lane Z partials [mt][r]
#pragma unroll
  for (int p = 0; p < 2; ++p) {
    __syncthreads();
    if (wm == p) {
#pragma unroll
      for (int nt = 0; nt < 4; ++nt) {
        const int coll = wn * 64 + nt * 16 + (lane & 15);
        const int colg = n0 + coll;
        const float bv = bias[colg];
        float qsv = 0.f;
        if (zflag) qsv = qsum[(bb * 16 + (colg >> 6)) * 64 + (colg & 63)];
#pragma unroll
        for (int mt = 0; mt < 4; ++mt) {
#pragma unroll
          for (int r = 0; r < 4; ++r) {
            const int rowl = mt * 16 + (lane >> 4) * 4 + r;   // 0..63 within pass
            float v = acc[mt][nt][r] + bv;
            if (act) v = (v > 0.f) ? (v + 1.f) : __expf(v);   // elu(x)+1
            cs[nt] += v;
            if (zflag) zp[mt][r] += v * qsv;
            smem[rowl * CT_S + coll] = f2bf(v);
          }
        }
      }
    }
    __syncthreads();
    // coalesced store of 64 rows: 16 threads x 16B = 256B contiguous per row
    {
      const int cc = (t & 15) * 8;
#pragma unroll
      for (int q = 0; q < 4; ++q) {
        const int row = q * 16 + (t >> 4);
        *(short8*)(C + (size_t)(m0 + p * 64 + row) * N + n0 + cc) =
            *(const short8*)&smem[row * CT_S + cc];
      }
    }
  }
  if (qsflag) {
#pragma unroll
    for (int nt = 0; nt < 4; ++nt) {
      float v = cs[nt];
      v += __shfl_xor(v, 16);
      v += __shfl_xor(v, 32);   // lanes 0..15 hold the full 64-row column sum
      if (lane < 16) {
        const int colg = n0 + wn * 64 + nt * 16 + lane;
        atomicAdd(&qsum[(bb * 16 + (colg >> 6)) * 64 + (colg & 63)], v);
      }
    }
  }
  if (zflag) {
    // wave wn covers ALL 64 cols of head h: reduce over lane&15 -> full Z per row
    const int h = (n0 >> 6) + wn;
#pragma unroll
    for (int mt = 0; mt < 4; ++mt) {
#pragma unroll
      for (int r = 0; r < 4; ++r) {
        float v = zp[mt][r];
        v += __shfl_xor(v, 1); v += __shfl_xor(v, 2);
        v += __shfl_xor(v, 4); v += __shfl_xor(v, 8);
        if ((lane & 15) == 0) {
          const int rowg = m0 + wm * 64 + mt * 16 + (lane >> 4) * 4 + r;
          Z[((size_t)(bb * 16 + h)) * 4096 + (rowg & 4095)] = v;
        }
      }
    }
  }
}

// ---------------- KtQ partials: part[s][bh][e][d] = sum_{n in slab s} K[n,d]*Q[n,e] ----
#define KTS 136  // LDS row stride (ushorts): 272B = 16B-aligned, spreads frag-read banks
__global__ __launch_bounds__(256) void ktq_partial_kernel(const unsigned short* Qp,
                                                          const unsigned short* Kp,
                                                          float* part) {
  const int bh = blockIdx.x, b = bh >> 4, h = bh & 15;
  const int s = blockIdx.y;
  const unsigned short* Qh = Qp + (size_t)b * 4096 * 1024 + h * 64;
  const unsigned short* Kh = Kp + (size_t)b * 4096 * 1024 + h * 64;
  __shared__ unsigned short Kt[64 * KTS];
  __shared__ unsigned short Qt[64 * KTS];
  const int t = threadIdx.x, lane = t & 63, wave = t >> 6;
  floatx4 acc[4] = {};
  const int nlb = t >> 3;            // 0..31
  const int dblk = (t & 7) * 8;

  for (int c0 = s * 512; c0 < s * 512 + 512; c0 += 128) {
    __syncthreads();
#pragma unroll
    for (int it = 0; it < 4; ++it) {
      const int nl = it * 32 + nlb;
      const size_t goff = (size_t)(c0 + nl) * 1024 + dblk;
      short8 kv = *(const short8*)(Kh + goff);
      short8 qv = *(const short8*)(Qh + goff);
#pragma unroll
      for (int j = 0; j < 8; ++j) {
        Kt[(dblk + j) * KTS + nl] = (unsigned short)kv[j];
        Qt[(dblk + j) * KTS + nl] = (unsigned short)qv[j];
      }
    }
    __syncthreads();
#pragma unroll
    for (int ks = 0; ks < 4; ++ks) {
      const short8 a = *(const short8*)&Kt[(wave * 16 + (lane & 15)) * KTS + ks * 32 + (lane >> 4) * 8];
#pragma unroll
      for (int et = 0; et < 4; ++et) {
        const short8 bb = *(const short8*)&Qt[(et * 16 + (lane & 15)) * KTS + ks * 32 + (lane >> 4) * 8];
        acc[et] = __builtin_amdgcn_mfma_f32_16x16x32_bf16(a, bb, acc[et], 0, 0, 0);
      }
    }
  }
  float* outp = part + ((size_t)(s * 64 + bh)) * 4096;
#pragma unroll
  for (int et = 0; et < 4; ++et) {
    const int e = et * 16 + (lane & 15);
#pragma unroll
    for (int r = 0; r < 4; ++r) {
      const int d = wave * 16 + (lane >> 4) * 4 + r;
      outp[e * 64 + d] = acc[et][r];   // transposed store: [e][d]
    }
  }
}

// ---------------- reduce 8 slabs -> bf16 (KtQ)^T[e][d] ----------------
__global__ __launch_bounds__(256) void ktq_reduce_kernel(const float* __restrict__ part,
                                                         unsigned short* __restrict__ ktqt) {
  const int bh = blockIdx.x, t = threadIdx.x;
#pragma unroll
  for (int i = 0; i < 16; ++i) {
    const int idx = i * 256 + t;
    float s = 0.f;
#pragma unroll
    for (int sl = 0; sl < 8; ++sl) s += part[((size_t)(sl * 64 + bh)) * 4096 + idx];
    ktqt[(size_t)bh * 4096 + idx] = f2bf(s);
  }
}

// ---------------- U[b,n,h*64+e] = (sum_d V[n,d]*KtQ[d,e]) / (Z[b,h,n] + eps) ----------------
#define CTS 72  // kt_lds row stride: 144B = 16B-aligned, bank-spread
__global__ __launch_bounds__(256) void stagec_kernel(const unsigned short* Vp,
                                                     const unsigned short* ktqt,
                                                     const float* __restrict__ Z,
                                                     unsigned short* U) {
  const int bh = blockIdx.y, b = bh >> 4, h = bh & 15;
  const int n0 = blockIdx.x * 256;
  __shared__ unsigned short kt_lds[64 * CTS];
  __shared__ float zbuf[256];
  const int t = threadIdx.x, lane = t & 63, wave = t >> 6;

  {
    const unsigned short* src = ktqt + (size_t)bh * 4096;
    const int row = t >> 2, seg = (t & 3) * 16;
    *(short8*)&kt_lds[row * CTS + seg] = *(const short8*)(src + row * 64 + seg);
    *(short8*)&kt_lds[row * CTS + seg + 8] = *(const short8*)(src + row * 64 + seg + 8);
  }
  zbuf[t] = Z[(size_t)bh * 4096 + n0 + t];
  __syncthreads();

  const unsigned short* Vh = Vp + (size_t)b * 4096 * 1024 + h * 64;
  floatx4 acc[4][4] = {};
#pragma unroll
  for (int ks = 0; ks < 2; ++ks) {
    short8 bfr[4];
#pragma unroll
    for (int et = 0; et < 4; ++et)
      bfr[et] = *(const short8*)&kt_lds[(et * 16 + (lane & 15)) * CTS + ks * 32 + (lane >> 4) * 8];
#pragma unroll
    for (int mt = 0; mt < 4; ++mt) {
      const short8 a = *(const short8*)(Vh + (size_t)(n0 + wave * 64 + mt * 16 + (lane & 15)) * 1024 +
                                        ks * 32 + (lane >> 4) * 8);
#pragma unroll
      for (int et = 0; et < 4; ++et)
        acc[mt][et] = __builtin_amdgcn_mfma_f32_16x16x32_bf16(a, bfr[et], acc[mt][et], 0, 0, 0);
    }
  }
#pragma unroll
  for (int mt = 0; mt < 4; ++mt) {
#pragma unroll
    for (int r = 0; r < 4; ++r) {
      const int rl = wave * 64 + mt * 16 + (lane >> 4) * 4 + r;
      const float inv = 1.0f / (zbuf[rl] + 1e-9f);
#pragma unroll
      for (int et = 0; et < 4; ++et) {
        const int e = et * 16 + (lane & 15);
        U[((size_t)b * 4096 + n0 + rl) * 1024 + h * 64 + e] = f2bf(acc[mt][et][r] * inv);
      }
    }
  }
}

// ---------------- residual + LayerNorm ----------------
__global__ __launch_bounds__(256) void ln_kernel(const float* query, const unsigned short* attn,
                                                 const float* gamma, const float* beta, float* out) {
  const int row = blockIdx.x, t = threadIdx.x;
  const float* qrow = query + (size_t)row * 1024;
  const unsigned short* arow = attn + (size_t)row * 1024;
  const float4 qv = *(const float4*)(qrow + t * 4);
  const ushortx4 av = *(const ushortx4*)(arow + t * 4);
  float x0 = qv.x + bf2f(av.x), x1 = qv.y + bf2f(av.y);
  float x2 = qv.z + bf2f(av.z), x3 = qv.w + bf2f(av.w);
  float s = x0 + x1 + x2 + x3;
  float s2 = x0 * x0 + x1 * x1 + x2 * x2 + x3 * x3;
  for (int off = 32; off > 0; off >>= 1) {
    s += __shfl_down(s, off);
    s2 += __shfl_down(s2, off);
  }
  __shared__ float lred[8];
  if ((t & 63) == 0) { lred[(t >> 6) * 2] = s; lred[(t >> 6) * 2 + 1] = s2; }
  __syncthreads();
  s = lred[0] + lred[2] + lred[4] + lred[6];
  s2 = lred[1] + lred[3] + lred[5] + lred[7];
  const float mu = s * (1.f / 1024.f);
  const float var = s2 * (1.f / 1024.f) - mu * mu;
  const float rstd = rsqrtf(var + 1e-6f);
  float4 o;
  o.x = (x0 - mu) * rstd * gamma[t * 4 + 0] + beta[t * 4 + 0];
  o.y = (x1 - mu) * rstd * gamma[t * 4 + 1] + beta[t * 4 + 1];
  o.z = (x2 - mu) * rstd * gamma[t * 4 + 2] + beta[t * 4 + 2];
  o.w = (x3 - mu) * rstd * gamma[t * 4 + 3] + beta[t * 4 + 3];
  *(float4*)(out + (size_t)row * 1024 + t * 4) = o;
}

// ---------------- launch ----------------
extern "C" void kernel_launch(void* const* d_in, const int* in_sizes, int n_in,
                              void* d_out, int out_size, void* d_ws, size_t ws_size,
                              hipStream_t stream) {
  const float* query = (const float*)d_in[0];
  const float* key_  = (const float*)d_in[1];
  const float* value = (const float*)d_in[2];
  const float* Wq = (const float*)d_in[3];
  const float* bq = (const float*)d_in[4];
  const float* Wk = (const float*)d_in[5];
  const float* bk = (const float*)d_in[6];
  const float* Wv = (const float*)d_in[7];
  const float* bv = (const float*)d_in[8];
  const float* Wo = (const float*)d_in[9];
  const float* bo = (const float*)d_in[10];
  const float* gamma = (const float*)d_in[11];
  const float* beta = (const float*)d_in[12];
  float* out = (float*)d_out;

  char* ws = (char*)d_ws;
  // ws layout (~137.6 MiB peak):
  //   abf (32MB, rotating bf16 A; aliased by ktq partials (8MB) then U) | Qp | Kp | Vp
  //   | WT (8MB) | qsum (16KB) | ktqt (512KB) | Z (1MB).  attn aliases Qp.
  unsigned short* abf = (unsigned short*)(ws + 0);
  unsigned short* Qp = (unsigned short*)(ws + 33554432);
  unsigned short* Kp = (unsigned short*)(ws + 67108864);
  unsigned short* Vp = (unsigned short*)(ws + 100663296);
  unsigned short* WT = (unsigned short*)(ws + 134217728);
  float* qsumP = (float*)(ws + 142606336);
  unsigned short* ktqtP = (unsigned short*)(ws + 142606336 + 16384);
  float* Zp = (float*)(ws + 142606336 + 16384 + 524288);
  float* part = (float*)abf;   // 8MB; live only between ktq_partial and ktq_reduce
  unsigned short* U = abf;     // abf dead after gemmV / part dead after reduce
  unsigned short* attn = Qp;   // Qp dead after ktq_partial

  dim3 blk(256);

  W4 w4; w4.w[0] = Wq; w4.w[1] = Wk; w4.w[2] = Wv; w4.w[3] = Wo;
  wtrans_kernel<<<dim3(32, 32, 4), blk, 0, stream>>>(w4, WT);

  // zero the fused q_sum accumulator (16 KB)
  hipMemsetAsync(qsumP, 0, 64 * 64 * sizeof(float), stream);

  const int convGrid = 8192;      // 16384*1024 / (256*8)
  const int gemmGrid = 128 * 8;   // (M/128)*(N/128)

  conv_kernel<<<convGrid, blk, 0, stream>>>(query, abf);
  gemm_bt_kernel<<<gemmGrid, blk, 0, stream>>>(abf, WT, bq, Qp, 1, 1, 0, qsumP, Zp,
                                               16384, 1024, 1024);

  conv_kernel<<<convGrid, blk, 0, stream>>>(key_, abf);
  gemm_bt_kernel<<<gemmGrid, blk, 0, stream>>>(abf, WT + 1024 * 1024, bk, Kp, 1, 0, 1,
                                               qsumP, Zp, 16384, 1024, 1024);

  conv_kernel<<<convGrid, blk, 0, stream>>>(value, abf);
  gemm_bt_kernel<<<gemmGrid, blk, 0, stream>>>(abf, WT + 2 * 1024 * 1024, bv, Vp, 0, 0, 0,
                                               qsumP, Zp, 16384, 1024, 1024);

  ktq_partial_kernel<<<dim3(64, 8), blk, 0, stream>>>(Qp, Kp, part);
  ktq_reduce_kernel<<<64, blk, 0, stream>>>(part, ktqtP);
  stagec_kernel<<<dim3(16, 64), blk, 0, stream>>>(Vp, ktqtP, Zp, U);

  gemm_bt_kernel<<<gemmGrid, blk, 0, stream>>>(U, WT + 3 * 1024 * 1024, bo, attn, 0, 0, 0,
                                               qsumP, Zp, 16384, 1024, 1024);

  ln_kernel<<<16384, blk, 0, stream>>>(query, attn, gamma, beta, out);
}